// Round 16
// baseline (718.119 us; speedup 1.0000x reference)
//
#include <hip/hip_runtime.h>

#define N_NODE 200000
#define EMB 64
#define N_EDGES 2000000
#define NROWS_TOTAL (2 * N_NODE)        // both graphs' rows concatenated
#define TOT_E (2 * N_EDGES)

// counting-sort geometry
#define BSHIFT 9
#define BROWS 512                                    // rows per bucket
#define NBUCK ((NROWS_TOTAL + BROWS - 1) / BROWS)    // 782
#define NB 1024                                      // binning blocks; == entries per bucket row
#define CHUNK ((TOT_E + NB - 1) / NB)                // 3907 edges per block
#define SCAN_N (NBUCK * NB)                          // 800768
#define MAXH 6144                                    // LDS edge buffer per bucket (mean ~5115)

typedef unsigned short bfu;
typedef __attribute__((ext_vector_type(8))) short bf16x8;
typedef __attribute__((ext_vector_type(4))) float f32x4;

__device__ __forceinline__ float bf2f(bfu u) { return __uint_as_float(((unsigned)u) << 16); }
__device__ __forceinline__ bfu f2bf(float f) {
    unsigned b = __float_as_uint(f);
    return (bfu)((b + 0x7FFF + ((b >> 16) & 1)) >> 16);   // RTNE, finite inputs
}

// out = emb * sigmoid(emb @ W + b) via MFMA. Per 16-node tile: A = bf16(x rows),
// B = bf16(W) preloaded per-wave from global (L2-hot), C/D layout per m89.
__global__ void gate_kernel(const float* __restrict__ emb,
                            const float* __restrict__ W,
                            const float* __restrict__ b,
                            bfu* __restrict__ out, int n) {
    int t = threadIdx.x;
    int w = t >> 6, lane = t & 63;
    int l16 = lane & 15, kg = lane >> 4;            // A row = l16, k-group = kg
    bf16x8 Bf[2][4];
#pragma unroll
    for (int kb = 0; kb < 2; ++kb)
#pragma unroll
        for (int nt = 0; nt < 4; ++nt) {
            bf16x8 f;
#pragma unroll
            for (int e = 0; e < 8; ++e)
                f[e] = (short)f2bf(W[(kb * 32 + kg * 8 + e) * 64 + nt * 16 + l16]);
            Bf[kb][nt] = f;
        }
    float bias[4];
#pragma unroll
    for (int nt = 0; nt < 4; ++nt) bias[nt] = b[nt * 16 + l16];
    const float4* e4 = (const float4*)emb;
#pragma unroll 1
    for (int it = 0; it < 4; ++it) {
        int tile = blockIdx.x * 16 + w * 4 + it;
        if (tile * 16 >= n) break;
        int arow = tile * 16 + l16;
        size_t ab = (size_t)arow * 16 + kg * 2;      // float4 index
        float4 a0 = e4[ab], a1 = e4[ab + 1];
        float4 a2 = e4[ab + 8], a3 = e4[ab + 9];
        bf16x8 A0, A1;
        A0[0] = (short)f2bf(a0.x); A0[1] = (short)f2bf(a0.y);
        A0[2] = (short)f2bf(a0.z); A0[3] = (short)f2bf(a0.w);
        A0[4] = (short)f2bf(a1.x); A0[5] = (short)f2bf(a1.y);
        A0[6] = (short)f2bf(a1.z); A0[7] = (short)f2bf(a1.w);
        A1[0] = (short)f2bf(a2.x); A1[1] = (short)f2bf(a2.y);
        A1[2] = (short)f2bf(a2.z); A1[3] = (short)f2bf(a2.w);
        A1[4] = (short)f2bf(a3.x); A1[5] = (short)f2bf(a3.y);
        A1[6] = (short)f2bf(a3.z); A1[7] = (short)f2bf(a3.w);
        f32x4 acc[4];
#pragma unroll
        for (int nt = 0; nt < 4; ++nt) {
            acc[nt] = (f32x4){0.f, 0.f, 0.f, 0.f};
            acc[nt] = __builtin_amdgcn_mfma_f32_16x16x32_bf16(A0, Bf[0][nt], acc[nt], 0, 0, 0);
            acc[nt] = __builtin_amdgcn_mfma_f32_16x16x32_bf16(A1, Bf[1][nt], acc[nt], 0, 0, 0);
        }
#pragma unroll
        for (int nt = 0; nt < 4; ++nt) {
#pragma unroll
            for (int r = 0; r < 4; ++r) {
                int orow = tile * 16 + kg * 4 + r;
                int col = nt * 16 + l16;
                float s = acc[nt][r] + bias[nt];
                float g = 1.0f / (1.0f + __expf(-s));
                float xv = emb[(size_t)orow * 64 + col];
                out[(size_t)orow * 64 + col] = f2bf(xv * g);
            }
        }
    }
}

// phase 1: per-block LDS bucket histogram -> bc[bucket*NB + blk]
__global__ void binA_kernel(const int* __restrict__ item_rows,
                            const int* __restrict__ user_rows,
                            int* __restrict__ bc) {
    __shared__ int h[NBUCK];
    int t = threadIdx.x, blk = blockIdx.x;
    for (int k = t; k < NBUCK; k += 256) h[k] = 0;
    __syncthreads();
    int lo = blk * CHUNK, hi = min(lo + CHUNK, TOT_E);
    for (int i = lo + t; i < hi; i += 256) {
        int g = (i < N_EDGES) ? item_rows[i] : (N_NODE + user_rows[i - N_EDGES]);
        atomicAdd(&h[g >> BSHIFT], 1);
    }
    __syncthreads();
    for (int k = t; k < NBUCK; k += 256) bc[k * NB + blk] = h[k];
}

// scan1: one block per bucket (NB==1024 entries). Outputs padded bucket total + real bucket total.
__global__ void scan1_kernel(const int* __restrict__ bc, int* __restrict__ bsumP,
                             int* __restrict__ btot) {
    int b = blockIdx.x, t = threadIdx.x;
    int base = b * NB + t * 4;
    int sR = 0, sP = 0;
#pragma unroll
    for (int k = 0; k < 4; ++k) {
        int c = bc[base + k];
        sR += c;
        sP += (c + 7) & ~7;
    }
#pragma unroll
    for (int off = 32; off; off >>= 1) {
        sR += __shfl_xor(sR, off);
        sP += __shfl_xor(sP, off);
    }
    __shared__ int wsR[4], wsP[4];
    int lane = t & 63, w = t >> 6;
    if (lane == 0) { wsR[w] = sR; wsP[w] = sP; }
    __syncthreads();
    if (t == 0) {
        btot[b] = wsR[0] + wsR[1] + wsR[2] + wsR[3];
        bsumP[b] = wsP[0] + wsP[1] + wsP[2] + wsP[3];
    }
}

// scan2: dual exclusive scan over NBUCK entries (1024 threads)
__global__ void scan2_kernel(const int* __restrict__ bsumP, const int* __restrict__ btot,
                             int* __restrict__ boffP, int* __restrict__ bbase) {
    __shared__ int sh[1024];
    int t = threadIdx.x;
    int vP = (t < NBUCK) ? bsumP[t] : 0;
    sh[t] = vP;
    __syncthreads();
    for (int off = 1; off < 1024; off <<= 1) {
        int u = (t >= off) ? sh[t - off] : 0;
        __syncthreads();
        sh[t] += u;
        __syncthreads();
    }
    if (t < NBUCK) boffP[t] = sh[t] - vP;
    if (t == 1023) boffP[NBUCK] = sh[1023];
    __syncthreads();
    int vR = (t < NBUCK) ? btot[t] : 0;
    sh[t] = vR;
    __syncthreads();
    for (int off = 1; off < 1024; off <<= 1) {
        int u = (t >= off) ? sh[t - off] : 0;
        __syncthreads();
        sh[t] += u;
        __syncthreads();
    }
    if (t < NBUCK) bbase[t] = sh[t] - vR;
}

// scan3: per-entry PADDED exclusive offsets within bucket, based at boffP[bucket]
__global__ void scan3_kernel(const int* __restrict__ bc, const int* __restrict__ boffP,
                             int* __restrict__ soffP) {
    int b = blockIdx.x, t = threadIdx.x;
    int lane = t & 63, w = t >> 6;
    int base = b * NB + t * 4;
    int p[4];
#pragma unroll
    for (int k = 0; k < 4; ++k) p[k] = (bc[base + k] + 7) & ~7;
    int e1 = p[0], e2 = p[0] + p[1], e3 = p[0] + p[1] + p[2];
    int tsum = e3 + p[3];
    int incl = tsum;
#pragma unroll
    for (int off = 1; off < 64; off <<= 1) {
        int u = __shfl_up(incl, off);
        if (lane >= off) incl += u;
    }
    int excl = incl - tsum;
    __shared__ int wsum[4];
    if (lane == 63) wsum[w] = incl;
    __syncthreads();
    int woff = 0;
    for (int k = 0; k < 4; ++k) if (k < w) woff += wsum[k];
    int g = boffP[b] + woff + excl;
    soffP[base + 0] = g;
    soffP[base + 1] = g + e1;
    soffP[base + 2] = g + e2;
    soffP[base + 3] = g + e3;
}

// phase 2: LDS counting sort + burst write. Histogram comes FREE from bc.
__global__ void binB_kernel(const int* __restrict__ item_rows, const int* __restrict__ item_cols,
                            const float* __restrict__ item_vals,
                            const int* __restrict__ user_rows, const int* __restrict__ user_cols,
                            const float* __restrict__ user_vals,
                            const int* __restrict__ bc, const int* __restrict__ soffP,
                            int2* __restrict__ staged) {
    __shared__ int2 ebuf[CHUNK];         // bucket-sorted edges (31.3 KB)
    __shared__ unsigned short sbk[CHUNK];// slot -> bucket (7.8 KB)
    __shared__ int lbase[NBUCK + 1];
    __shared__ int lcur[NBUCK];
    __shared__ int gb[NBUCK];
    __shared__ int wsum[4];
    int t = threadIdx.x, blk = blockIdx.x;
    for (int k = t; k < NBUCK; k += 256) gb[k] = soffP[k * NB + blk];
    {
        int i0 = t * 4;
        int p0 = (i0 < NBUCK) ? bc[i0 * NB + blk] : 0;
        int p1 = (i0 + 1 < NBUCK) ? bc[(i0 + 1) * NB + blk] : 0;
        int p2 = (i0 + 2 < NBUCK) ? bc[(i0 + 2) * NB + blk] : 0;
        int p3 = (i0 + 3 < NBUCK) ? bc[(i0 + 3) * NB + blk] : 0;
        int tsum = p0 + p1 + p2 + p3;
        int lane = t & 63, w = t >> 6;
        int incl = tsum;
#pragma unroll
        for (int off = 1; off < 64; off <<= 1) {
            int u = __shfl_up(incl, off);
            if (lane >= off) incl += u;
        }
        if (lane == 63) wsum[w] = incl;
        __syncthreads();
        int woff = 0;
        for (int k = 0; k < w; ++k) woff += wsum[k];
        int excl = woff + incl - tsum;
        if (i0 < NBUCK) { lbase[i0] = excl; lcur[i0] = excl; }
        if (i0 + 1 < NBUCK) { lbase[i0 + 1] = excl + p0; lcur[i0 + 1] = excl + p0; }
        if (i0 + 2 < NBUCK) { lbase[i0 + 2] = excl + p0 + p1; lcur[i0 + 2] = excl + p0 + p1; }
        if (i0 + 3 < NBUCK) { lbase[i0 + 3] = excl + p0 + p1 + p2; lcur[i0 + 3] = excl + p0 + p1 + p2; }
        if (t == 255) lbase[NBUCK] = excl + tsum;   // == edges in this chunk
    }
    __syncthreads();
    int lo = blk * CHUNK, hi = min(lo + CHUNK, TOT_E);
    int cnt = hi - lo;
    for (int i = lo + t; i < hi; i += 256) {
        int g, c; float v;
        if (i < N_EDGES) { g = item_rows[i]; c = item_cols[i]; v = item_vals[i]; }
        else { int j = i - N_EDGES; g = N_NODE + user_rows[j]; c = user_cols[j]; v = user_vals[j]; }
        int bk = g >> BSHIFT;
        int s = atomicAdd(&lcur[bk], 1);
        ebuf[s] = make_int2(((g & (BROWS - 1)) << 18) | c, __float_as_int(v));
        sbk[s] = (unsigned short)bk;
    }
    __syncthreads();
    for (int j = t; j < cnt; j += 256) {
        int k = sbk[j];
        staged[gb[k] + (j - lbase[k])] = ebuf[j];
    }
    for (int k = t; k < NBUCK; k += 256) {
        int c = lbase[k + 1] - lbase[k];
        int s = gb[k] + c, e = gb[k] + ((c + 7) & ~7);
        for (int q = s; q < e; ++q) staged[q] = make_int2(-1, 0);
    }
}

// phase 3: one WG per 512-row bucket, reads ONLY its own staged range.
__global__ void finalize_kernel(const int2* __restrict__ staged, const int* __restrict__ boffP,
                                const int* __restrict__ bbase,
                                int* __restrict__ row_ptr, int2* __restrict__ ecv) {
    __shared__ int hist[BROWS];
    __shared__ int start[BROWS + 1];
    __shared__ int2 ebuf[MAXH];
    __shared__ int wsum[4];
    int b = blockIdx.x, t = threadIdx.x;
    int base = boffP[b], end = boffP[b + 1];
    int ebase = bbase[b];
    hist[t * 2] = 0; hist[t * 2 + 1] = 0;
    __syncthreads();
    for (int k = base + t; k < end; k += 256) {
        int gx = staged[k].x;
        if (gx >= 0) atomicAdd(&hist[gx >> 18], 1);
    }
    __syncthreads();
    int i0 = t * 2;
    int c0 = hist[i0], c1 = hist[i0 + 1];
    int tsum = c0 + c1;
    int lane = t & 63, w = t >> 6;
    int incl = tsum;
#pragma unroll
    for (int off = 1; off < 64; off <<= 1) {
        int u = __shfl_up(incl, off);
        if (lane >= off) incl += u;
    }
    if (lane == 63) wsum[w] = incl;
    __syncthreads();
    int woff = 0;
    for (int k = 0; k < w; ++k) woff += wsum[k];
    int excl = woff + incl - tsum;
    start[i0] = excl; start[i0 + 1] = excl + c0;
    if (t == 255) start[BROWS] = excl + tsum;
    __syncthreads();
    int tot = start[BROWS];
#pragma unroll
    for (int q = 0; q < 2; ++q) {
        int r = i0 + q;
        int g = (b << BSHIFT) + r;
        if (g < NROWS_TOTAL) row_ptr[g] = ebase + start[r];
    }
    if (b == 0 && t == 0) row_ptr[NROWS_TOTAL] = TOT_E;
    if (tot <= MAXH) {
        hist[i0] = start[i0]; hist[i0 + 1] = start[i0 + 1];
        __syncthreads();
        for (int k = base + t; k < end; k += 256) {
            int2 p = staged[k];
            if (p.x < 0) continue;
            int l = atomicAdd(&hist[p.x >> 18], 1);
            ebuf[l] = make_int2(p.x & 0x3FFFF, p.y);
        }
        __syncthreads();
        for (int j = t; j < tot; j += 256) ecv[ebase + j] = ebuf[j];
    } else {
        hist[i0] = ebase + start[i0]; hist[i0 + 1] = ebase + start[i0 + 1];
        __syncthreads();
        for (int k = base + t; k < end; k += 256) {
            int2 p = staged[k];
            if (p.x < 0) continue;
            int pos = atomicAdd(&hist[p.x >> 18], 1);
            ecv[pos] = make_int2(p.x & 0x3FFFF, p.y);
        }
    }
}

// y = A x: ONE ROW PER WAVE, 4 edges in flight (lane = (eg, l16)), no inner shfl.
__global__ void spmm_y(const int* __restrict__ row_ptr, const int2* __restrict__ ecv,
                       const bfu* __restrict__ x,
                       bfu* __restrict__ y, float* __restrict__ rinv, int n) {
    int t = threadIdx.x;
    int lane = t & 63;
    int eg = lane >> 4;          // edge slot 0..3
    int l16 = lane & 15;         // col quad
    int i = blockIdx.x * 4 + (t >> 6);
    if (i >= n) return;
    int s = row_ptr[i], e = row_ptr[i + 1];
    const ushort4* x4 = (const ushort4*)x;
    float4 a = make_float4(0.f, 0.f, 0.f, 0.f);
    for (int base = s; base < e; base += 4) {
        int idx = base + eg;
        int c = 0; float v = 0.0f;
        if (idx < e) { int2 p = ecv[idx]; c = p.x; v = __int_as_float(p.y); }
        ushort4 xv = x4[(size_t)c * 16 + l16];
        a.x += v * bf2f(xv.x); a.y += v * bf2f(xv.y);
        a.z += v * bf2f(xv.z); a.w += v * bf2f(xv.w);
    }
#pragma unroll
    for (int off = 16; off <= 32; off <<= 1) {
        a.x += __shfl_xor(a.x, off); a.y += __shfl_xor(a.y, off);
        a.z += __shfl_xor(a.z, off); a.w += __shfl_xor(a.w, off);
    }
    if (eg == 0) {
        ushort4 bv;
        bv.x = f2bf(a.x); bv.y = f2bf(a.y); bv.z = f2bf(a.z); bv.w = f2bf(a.w);
        ((ushort4*)y)[(size_t)i * 16 + l16] = bv;
    }
    float sq = a.x * a.x + a.y * a.y + a.z * a.z + a.w * a.w;
#pragma unroll
    for (int off = 1; off <= 8; off <<= 1) sq += __shfl_xor(sq, off);
    if (lane == 0) rinv[i] = 1.0f / fmaxf(sqrtf(sq), 1e-12f);
}

// channel-2 layer 3 fused with deferred sum: mixed = u0 + r1*y1 + r2*y2 + rinv3*(A y2)
__global__ void spmm_sum(const int* __restrict__ row_ptr, const int2* __restrict__ ecv,
                         const bfu* __restrict__ x /* = y2 */,
                         const bfu* __restrict__ u0, const bfu* __restrict__ y1,
                         const float* __restrict__ r1, const float* __restrict__ r2,
                         float* __restrict__ mixed, int n) {
    int t = threadIdx.x;
    int lane = t & 63;
    int eg = lane >> 4;
    int l16 = lane & 15;
    int i = blockIdx.x * 4 + (t >> 6);
    if (i >= n) return;
    int s = row_ptr[i], e = row_ptr[i + 1];
    const ushort4* x4 = (const ushort4*)x;
    float4 a = make_float4(0.f, 0.f, 0.f, 0.f);
    for (int base = s; base < e; base += 4) {
        int idx = base + eg;
        int c = 0; float v = 0.0f;
        if (idx < e) { int2 p = ecv[idx]; c = p.x; v = __int_as_float(p.y); }
        ushort4 xv = x4[(size_t)c * 16 + l16];
        a.x += v * bf2f(xv.x); a.y += v * bf2f(xv.y);
        a.z += v * bf2f(xv.z); a.w += v * bf2f(xv.w);
    }
#pragma unroll
    for (int off = 16; off <= 32; off <<= 1) {
        a.x += __shfl_xor(a.x, off); a.y += __shfl_xor(a.y, off);
        a.z += __shfl_xor(a.z, off); a.w += __shfl_xor(a.w, off);
    }
    float sq = a.x * a.x + a.y * a.y + a.z * a.z + a.w * a.w;
#pragma unroll
    for (int off = 1; off <= 8; off <<= 1) sq += __shfl_xor(sq, off);
    if (eg == 0) {
        float r3 = 1.0f / fmaxf(sqrtf(sq), 1e-12f);
        size_t o4 = (size_t)i * 16 + l16;
        float a1 = r1[i], a2 = r2[i];
        ushort4 b0 = ((const ushort4*)u0)[o4];
        ushort4 b1 = ((const ushort4*)y1)[o4];
        ushort4 b2 = ((const ushort4*)x)[o4];
        float4 o;
        o.x = bf2f(b0.x) + a1 * bf2f(b1.x) + a2 * bf2f(b2.x) + r3 * a.x;
        o.y = bf2f(b0.y) + a1 * bf2f(b1.y) + a2 * bf2f(b2.y) + r3 * a.y;
        o.z = bf2f(b0.z) + a1 * bf2f(b1.z) + a2 * bf2f(b2.z) + r3 * a.z;
        o.w = bf2f(b0.w) + a1 * bf2f(b1.w) + a2 * bf2f(b2.w) + r3 * a.w;
        ((float4*)mixed)[o4] = o;
    }
}

// channel-3 layer 3 fused with deferred sum + channel attention + mix
__global__ void spmm_mix(const int* __restrict__ row_ptr, const int2* __restrict__ ecv,
                         const bfu* __restrict__ x /* = y2 */,
                         const bfu* __restrict__ u0, const bfu* __restrict__ y1,
                         const float* __restrict__ r1, const float* __restrict__ r2,
                         float* __restrict__ mixed, const float* __restrict__ vvec,
                         float* __restrict__ score, int n) {
    int t = threadIdx.x;
    int lane = t & 63;
    int eg = lane >> 4;
    int l16 = lane & 15;
    int i = blockIdx.x * 4 + (t >> 6);
    if (i >= n) return;
    int s = row_ptr[i], e = row_ptr[i + 1];
    const ushort4* x4 = (const ushort4*)x;
    float4 a = make_float4(0.f, 0.f, 0.f, 0.f);
    for (int base = s; base < e; base += 4) {
        int idx = base + eg;
        int c = 0; float v = 0.0f;
        if (idx < e) { int2 p = ecv[idx]; c = p.x; v = __int_as_float(p.y); }
        ushort4 xv = x4[(size_t)c * 16 + l16];
        a.x += v * bf2f(xv.x); a.y += v * bf2f(xv.y);
        a.z += v * bf2f(xv.z); a.w += v * bf2f(xv.w);
    }
#pragma unroll
    for (int off = 16; off <= 32; off <<= 1) {
        a.x += __shfl_xor(a.x, off); a.y += __shfl_xor(a.y, off);
        a.z += __shfl_xor(a.z, off); a.w += __shfl_xor(a.w, off);
    }
    float sq = a.x * a.x + a.y * a.y + a.z * a.z + a.w * a.w;
#pragma unroll
    for (int off = 1; off <= 8; off <<= 1) sq += __shfl_xor(sq, off);
    float r3 = 1.0f / fmaxf(sqrtf(sq), 1e-12f);
    size_t o4 = (size_t)i * 16 + l16;
    float a1 = r1[i], a2s = r2[i];
    ushort4 b0 = ((const ushort4*)u0)[o4];
    ushort4 b1 = ((const ushort4*)y1)[o4];
    ushort4 b2 = ((const ushort4*)x)[o4];
    float4 a3;
    a3.x = bf2f(b0.x) + a1 * bf2f(b1.x) + a2s * bf2f(b2.x) + r3 * a.x;
    a3.y = bf2f(b0.y) + a1 * bf2f(b1.y) + a2s * bf2f(b2.y) + r3 * a.y;
    a3.z = bf2f(b0.z) + a1 * bf2f(b1.z) + a2s * bf2f(b2.z) + r3 * a.z;
    a3.w = bf2f(b0.w) + a1 * bf2f(b1.w) + a2s * bf2f(b2.w) + r3 * a.w;
    float4 a2 = ((float4*)mixed)[o4];
    float4 vv = ((const float4*)vvec)[l16];
    float w2 = a2.x * vv.x + a2.y * vv.y + a2.z * vv.z + a2.w * vv.w;
    float w3 = a3.x * vv.x + a3.y * vv.y + a3.z * vv.z + a3.w * vv.w;
#pragma unroll
    for (int off = 1; off <= 8; off <<= 1) {
        w2 += __shfl_xor(w2, off);
        w3 += __shfl_xor(w3, off);
    }
    float m = fmaxf(w2, w3);
    float x2 = __expf(w2 - m), x3 = __expf(w3 - m);
    float inv = 1.0f / (x2 + x3);
    float s2 = x2 * inv, s3 = x3 * inv;
    if (eg == 0) {
        float4 o;
        o.x = s2 * a2.x + s3 * a3.x; o.y = s2 * a2.y + s3 * a3.y;
        o.z = s2 * a2.z + s3 * a3.z; o.w = s2 * a2.w + s3 * a3.w;
        ((float4*)mixed)[o4] = o;
        if (l16 == 0) { score[(size_t)i * 2] = s2; score[(size_t)i * 2 + 1] = s3; }
    }
}

// v[k] = sum_j att_m[k][j] * att[j]
__global__ void vvec_kernel(const float* __restrict__ att_m, const float* __restrict__ att,
                            float* __restrict__ v) {
    int k = threadIdx.x;
    float s = 0.0f;
    for (int j = 0; j < 64; ++j) s += att_m[k * 64 + j] * att[j];
    v[k] = s;
}

extern "C" void kernel_launch(void* const* d_in, const int* in_sizes, int n_in,
                              void* d_out, int out_size, void* d_ws, size_t ws_size,
                              hipStream_t stream) {
    const float* user_emb = (const float*)d_in[0];
    const float* W0 = (const float*)d_in[1];
    const float* b0 = (const float*)d_in[2];
    const float* W1 = (const float*)d_in[3];
    const float* b1 = (const float*)d_in[4];
    const float* att = (const float*)d_in[5];
    const float* att_m = (const float*)d_in[6];
    const int* item_rows = (const int*)d_in[7];
    const int* item_cols = (const int*)d_in[8];
    const float* item_vals = (const float*)d_in[9];
    const int* user_rows = (const int*)d_in[10];
    const int* user_cols = (const int*)d_in[11];
    const float* user_vals = (const float*)d_in[12];

    float* out = (float*)d_out;
    float* mixed = out;                          // N*64 fp32, holds channel-2 sum then final
    float* score = out + (size_t)N_NODE * 64;

    char* w = (char*)d_ws;
    bfu* u0 = (bfu*)w;         w += (size_t)N_NODE * 64 * 2;
    bfu* y1 = (bfu*)w;         w += (size_t)N_NODE * 64 * 2;
    bfu* y2 = (bfu*)w;         w += (size_t)N_NODE * 64 * 2;
    float* rv1 = (float*)w;    w += (size_t)N_NODE * 4;
    float* rv2 = (float*)w;    w += (size_t)N_NODE * 4;
    int* row_ptr = (int*)w;    w += ((size_t)NROWS_TOTAL + 64) * 4;
    int2* ecv = (int2*)w;      w += (size_t)TOT_E * 8;
    float* vvec = (float*)w;   w += 256;
    int* bc = (int*)w;         w += (size_t)SCAN_N * 4;
    int* soffP = (int*)w;      w += (size_t)SCAN_N * 4;
    int* bsumP = (int*)w;      w += (NBUCK + 8) * 4;
    int* btot = (int*)w;       w += (NBUCK + 8) * 4;
    int* boffP = (int*)w;      w += (NBUCK + 8) * 4;
    int* bbase = (int*)w;      w += (NBUCK + 8) * 4;
    // staged overlays u0..rv2 (78.4MB >= padded worst case 76.9MB), dead during build
    int2* staged = (int2*)u0;

    const int NB4 = (N_NODE + 3) / 4;            // one row per wave
    const int GATE_B = (N_NODE / 16 + 15) / 16;
    const int* rp_item = row_ptr;
    const int* rp_user = row_ptr + N_NODE;

    // counting-sort CSR build, padded line-exclusive staging, LDS-sorted burst writes
    binA_kernel<<<NB, 256, 0, stream>>>(item_rows, user_rows, bc);
    scan1_kernel<<<NBUCK, 256, 0, stream>>>(bc, bsumP, btot);
    scan2_kernel<<<1, 1024, 0, stream>>>(bsumP, btot, boffP, bbase);
    scan3_kernel<<<NBUCK, 256, 0, stream>>>(bc, boffP, soffP);
    binB_kernel<<<NB, 256, 0, stream>>>(item_rows, item_cols, item_vals,
                                        user_rows, user_cols, user_vals, bc, soffP, staged);
    finalize_kernel<<<NBUCK, 256, 0, stream>>>(staged, boffP, bbase, row_ptr, ecv);
    vvec_kernel<<<1, 64, 0, stream>>>(att_m, att, vvec);

    // channel 2: item graph -> fp32 sum in mixed (layer 3 fused)
    gate_kernel<<<GATE_B, 256, 0, stream>>>(user_emb, W0, b0, u0, N_NODE);
    spmm_y<<<NB4, 256, 0, stream>>>(rp_item, ecv, u0, y1, rv1, N_NODE);
    spmm_y<<<NB4, 256, 0, stream>>>(rp_item, ecv, y1, y2, rv2, N_NODE);
    spmm_sum<<<NB4, 256, 0, stream>>>(rp_item, ecv, y2, u0, y1, rv1, rv2, mixed, N_NODE);

    // channel 3: user graph, layer 3 fused with sum + attention + mix
    gate_kernel<<<GATE_B, 256, 0, stream>>>(user_emb, W1, b1, u0, N_NODE);
    spmm_y<<<NB4, 256, 0, stream>>>(rp_user, ecv, u0, y1, rv1, N_NODE);
    spmm_y<<<NB4, 256, 0, stream>>>(rp_user, ecv, y1, y2, rv2, N_NODE);
    spmm_mix<<<NB4, 256, 0, stream>>>(rp_user, ecv, y2, u0, y1, rv1, rv2,
                                      mixed, vvec, score, N_NODE);
}

// Round 17
// 442.629 us; speedup vs baseline: 1.6224x; 1.6224x over previous
//
#include <hip/hip_runtime.h>

#define N_NODE 200000
#define EMB 64
#define N_EDGES 2000000
#define NROWS_TOTAL (2 * N_NODE)        // both graphs' rows concatenated
#define TOT_E (2 * N_EDGES)

// counting-sort geometry
#define BSHIFT 9
#define BROWS 512                                    // rows per bucket
#define NBUCK ((NROWS_TOTAL + BROWS - 1) / BROWS)    // 782
#define NB 1024                                      // binning blocks; == entries per bucket row
#define CHUNK ((TOT_E + NB - 1) / NB)                // 3907 edges per block
#define SCAN_N (NBUCK * NB)                          // 800768
#define MAXH 6144                                    // LDS edge buffer per bucket (mean ~5115)

typedef unsigned short bfu;
typedef __attribute__((ext_vector_type(8))) short bf16x8;
typedef __attribute__((ext_vector_type(4))) float f32x4;

__device__ __forceinline__ float bf2f(bfu u) { return __uint_as_float(((unsigned)u) << 16); }
__device__ __forceinline__ bfu f2bf(float f) {
    unsigned b = __float_as_uint(f);
    return (bfu)((b + 0x7FFF + ((b >> 16) & 1)) >> 16);   // RTNE, finite inputs
}

// out = emb * sigmoid(emb @ W + b) via MFMA. Per 16-node tile: A = bf16(x rows),
// B = bf16(W) preloaded per-wave from global (L2-hot), C/D layout per m89.
__global__ void gate_kernel(const float* __restrict__ emb,
                            const float* __restrict__ W,
                            const float* __restrict__ b,
                            bfu* __restrict__ out, int n) {
    int t = threadIdx.x;
    int w = t >> 6, lane = t & 63;
    int l16 = lane & 15, kg = lane >> 4;            // A row = l16, k-group = kg
    bf16x8 Bf[2][4];
#pragma unroll
    for (int kb = 0; kb < 2; ++kb)
#pragma unroll
        for (int nt = 0; nt < 4; ++nt) {
            bf16x8 f;
#pragma unroll
            for (int e = 0; e < 8; ++e)
                f[e] = (short)f2bf(W[(kb * 32 + kg * 8 + e) * 64 + nt * 16 + l16]);
            Bf[kb][nt] = f;
        }
    float bias[4];
#pragma unroll
    for (int nt = 0; nt < 4; ++nt) bias[nt] = b[nt * 16 + l16];
    const float4* e4 = (const float4*)emb;
#pragma unroll 1
    for (int it = 0; it < 4; ++it) {
        int tile = blockIdx.x * 16 + w * 4 + it;
        if (tile * 16 >= n) break;
        int arow = tile * 16 + l16;
        size_t ab = (size_t)arow * 16 + kg * 2;      // float4 index
        float4 a0 = e4[ab], a1 = e4[ab + 1];
        float4 a2 = e4[ab + 8], a3 = e4[ab + 9];
        bf16x8 A0, A1;
        A0[0] = (short)f2bf(a0.x); A0[1] = (short)f2bf(a0.y);
        A0[2] = (short)f2bf(a0.z); A0[3] = (short)f2bf(a0.w);
        A0[4] = (short)f2bf(a1.x); A0[5] = (short)f2bf(a1.y);
        A0[6] = (short)f2bf(a1.z); A0[7] = (short)f2bf(a1.w);
        A1[0] = (short)f2bf(a2.x); A1[1] = (short)f2bf(a2.y);
        A1[2] = (short)f2bf(a2.z); A1[3] = (short)f2bf(a2.w);
        A1[4] = (short)f2bf(a3.x); A1[5] = (short)f2bf(a3.y);
        A1[6] = (short)f2bf(a3.z); A1[7] = (short)f2bf(a3.w);
        f32x4 acc[4];
#pragma unroll
        for (int nt = 0; nt < 4; ++nt) {
            acc[nt] = (f32x4){0.f, 0.f, 0.f, 0.f};
            acc[nt] = __builtin_amdgcn_mfma_f32_16x16x32_bf16(A0, Bf[0][nt], acc[nt], 0, 0, 0);
            acc[nt] = __builtin_amdgcn_mfma_f32_16x16x32_bf16(A1, Bf[1][nt], acc[nt], 0, 0, 0);
        }
#pragma unroll
        for (int nt = 0; nt < 4; ++nt) {
#pragma unroll
            for (int r = 0; r < 4; ++r) {
                int orow = tile * 16 + kg * 4 + r;
                int col = nt * 16 + l16;
                float s = acc[nt][r] + bias[nt];
                float g = 1.0f / (1.0f + __expf(-s));
                float xv = emb[(size_t)orow * 64 + col];
                out[(size_t)orow * 64 + col] = f2bf(xv * g);
            }
        }
    }
}

// phase 1: per-block LDS bucket histogram -> bc[bucket*NB + blk]
__global__ void binA_kernel(const int* __restrict__ item_rows,
                            const int* __restrict__ user_rows,
                            int* __restrict__ bc) {
    __shared__ int h[NBUCK];
    int t = threadIdx.x, blk = blockIdx.x;
    for (int k = t; k < NBUCK; k += 256) h[k] = 0;
    __syncthreads();
    int lo = blk * CHUNK, hi = min(lo + CHUNK, TOT_E);
    for (int i = lo + t; i < hi; i += 256) {
        int g = (i < N_EDGES) ? item_rows[i] : (N_NODE + user_rows[i - N_EDGES]);
        atomicAdd(&h[g >> BSHIFT], 1);
    }
    __syncthreads();
    for (int k = t; k < NBUCK; k += 256) bc[k * NB + blk] = h[k];
}

// scan1: one block per bucket (NB==1024 entries). Outputs padded bucket total + real bucket total.
__global__ void scan1_kernel(const int* __restrict__ bc, int* __restrict__ bsumP,
                             int* __restrict__ btot) {
    int b = blockIdx.x, t = threadIdx.x;
    int base = b * NB + t * 4;
    int sR = 0, sP = 0;
#pragma unroll
    for (int k = 0; k < 4; ++k) {
        int c = bc[base + k];
        sR += c;
        sP += (c + 7) & ~7;
    }
#pragma unroll
    for (int off = 32; off; off >>= 1) {
        sR += __shfl_xor(sR, off);
        sP += __shfl_xor(sP, off);
    }
    __shared__ int wsR[4], wsP[4];
    int lane = t & 63, w = t >> 6;
    if (lane == 0) { wsR[w] = sR; wsP[w] = sP; }
    __syncthreads();
    if (t == 0) {
        btot[b] = wsR[0] + wsR[1] + wsR[2] + wsR[3];
        bsumP[b] = wsP[0] + wsP[1] + wsP[2] + wsP[3];
    }
}

// scan2: dual exclusive scan over NBUCK entries (1024 threads)
__global__ void scan2_kernel(const int* __restrict__ bsumP, const int* __restrict__ btot,
                             int* __restrict__ boffP, int* __restrict__ bbase) {
    __shared__ int sh[1024];
    int t = threadIdx.x;
    int vP = (t < NBUCK) ? bsumP[t] : 0;
    sh[t] = vP;
    __syncthreads();
    for (int off = 1; off < 1024; off <<= 1) {
        int u = (t >= off) ? sh[t - off] : 0;
        __syncthreads();
        sh[t] += u;
        __syncthreads();
    }
    if (t < NBUCK) boffP[t] = sh[t] - vP;
    if (t == 1023) boffP[NBUCK] = sh[1023];
    __syncthreads();
    int vR = (t < NBUCK) ? btot[t] : 0;
    sh[t] = vR;
    __syncthreads();
    for (int off = 1; off < 1024; off <<= 1) {
        int u = (t >= off) ? sh[t - off] : 0;
        __syncthreads();
        sh[t] += u;
        __syncthreads();
    }
    if (t < NBUCK) bbase[t] = sh[t] - vR;
}

// scan3: per-entry PADDED exclusive offsets within bucket, based at boffP[bucket]
__global__ void scan3_kernel(const int* __restrict__ bc, const int* __restrict__ boffP,
                             int* __restrict__ soffP) {
    int b = blockIdx.x, t = threadIdx.x;
    int lane = t & 63, w = t >> 6;
    int base = b * NB + t * 4;
    int p[4];
#pragma unroll
    for (int k = 0; k < 4; ++k) p[k] = (bc[base + k] + 7) & ~7;
    int e1 = p[0], e2 = p[0] + p[1], e3 = p[0] + p[1] + p[2];
    int tsum = e3 + p[3];
    int incl = tsum;
#pragma unroll
    for (int off = 1; off < 64; off <<= 1) {
        int u = __shfl_up(incl, off);
        if (lane >= off) incl += u;
    }
    int excl = incl - tsum;
    __shared__ int wsum[4];
    if (lane == 63) wsum[w] = incl;
    __syncthreads();
    int woff = 0;
    for (int k = 0; k < 4; ++k) if (k < w) woff += wsum[k];
    int g = boffP[b] + woff + excl;
    soffP[base + 0] = g;
    soffP[base + 1] = g + e1;
    soffP[base + 2] = g + e2;
    soffP[base + 3] = g + e3;
}

// phase 2: LDS counting sort + burst write. Histogram comes FREE from bc.
__global__ void binB_kernel(const int* __restrict__ item_rows, const int* __restrict__ item_cols,
                            const float* __restrict__ item_vals,
                            const int* __restrict__ user_rows, const int* __restrict__ user_cols,
                            const float* __restrict__ user_vals,
                            const int* __restrict__ bc, const int* __restrict__ soffP,
                            int2* __restrict__ staged) {
    __shared__ int2 ebuf[CHUNK];         // bucket-sorted edges (31.3 KB)
    __shared__ unsigned short sbk[CHUNK];// slot -> bucket (7.8 KB)
    __shared__ int lbase[NBUCK + 1];
    __shared__ int lcur[NBUCK];
    __shared__ int gb[NBUCK];
    __shared__ int wsum[4];
    int t = threadIdx.x, blk = blockIdx.x;
    for (int k = t; k < NBUCK; k += 256) gb[k] = soffP[k * NB + blk];
    {
        int i0 = t * 4;
        int p0 = (i0 < NBUCK) ? bc[i0 * NB + blk] : 0;
        int p1 = (i0 + 1 < NBUCK) ? bc[(i0 + 1) * NB + blk] : 0;
        int p2 = (i0 + 2 < NBUCK) ? bc[(i0 + 2) * NB + blk] : 0;
        int p3 = (i0 + 3 < NBUCK) ? bc[(i0 + 3) * NB + blk] : 0;
        int tsum = p0 + p1 + p2 + p3;
        int lane = t & 63, w = t >> 6;
        int incl = tsum;
#pragma unroll
        for (int off = 1; off < 64; off <<= 1) {
            int u = __shfl_up(incl, off);
            if (lane >= off) incl += u;
        }
        if (lane == 63) wsum[w] = incl;
        __syncthreads();
        int woff = 0;
        for (int k = 0; k < w; ++k) woff += wsum[k];
        int excl = woff + incl - tsum;
        if (i0 < NBUCK) { lbase[i0] = excl; lcur[i0] = excl; }
        if (i0 + 1 < NBUCK) { lbase[i0 + 1] = excl + p0; lcur[i0 + 1] = excl + p0; }
        if (i0 + 2 < NBUCK) { lbase[i0 + 2] = excl + p0 + p1; lcur[i0 + 2] = excl + p0 + p1; }
        if (i0 + 3 < NBUCK) { lbase[i0 + 3] = excl + p0 + p1 + p2; lcur[i0 + 3] = excl + p0 + p1 + p2; }
        if (t == 255) lbase[NBUCK] = excl + tsum;   // == edges in this chunk
    }
    __syncthreads();
    int lo = blk * CHUNK, hi = min(lo + CHUNK, TOT_E);
    int cnt = hi - lo;
    for (int i = lo + t; i < hi; i += 256) {
        int g, c; float v;
        if (i < N_EDGES) { g = item_rows[i]; c = item_cols[i]; v = item_vals[i]; }
        else { int j = i - N_EDGES; g = N_NODE + user_rows[j]; c = user_cols[j]; v = user_vals[j]; }
        int bk = g >> BSHIFT;
        int s = atomicAdd(&lcur[bk], 1);
        ebuf[s] = make_int2(((g & (BROWS - 1)) << 18) | c, __float_as_int(v));
        sbk[s] = (unsigned short)bk;
    }
    __syncthreads();
    for (int j = t; j < cnt; j += 256) {
        int k = sbk[j];
        staged[gb[k] + (j - lbase[k])] = ebuf[j];
    }
    for (int k = t; k < NBUCK; k += 256) {
        int c = lbase[k + 1] - lbase[k];
        int s = gb[k] + c, e = gb[k] + ((c + 7) & ~7);
        for (int q = s; q < e; ++q) staged[q] = make_int2(-1, 0);
    }
}

// phase 3: one WG per 512-row bucket, reads ONLY its own staged range.
__global__ void finalize_kernel(const int2* __restrict__ staged, const int* __restrict__ boffP,
                                const int* __restrict__ bbase,
                                int* __restrict__ row_ptr, int2* __restrict__ ecv) {
    __shared__ int hist[BROWS];
    __shared__ int start[BROWS + 1];
    __shared__ int2 ebuf[MAXH];
    __shared__ int wsum[4];
    int b = blockIdx.x, t = threadIdx.x;
    int base = boffP[b], end = boffP[b + 1];
    int ebase = bbase[b];
    hist[t * 2] = 0; hist[t * 2 + 1] = 0;
    __syncthreads();
    for (int k = base + t; k < end; k += 256) {
        int gx = staged[k].x;
        if (gx >= 0) atomicAdd(&hist[gx >> 18], 1);
    }
    __syncthreads();
    int i0 = t * 2;
    int c0 = hist[i0], c1 = hist[i0 + 1];
    int tsum = c0 + c1;
    int lane = t & 63, w = t >> 6;
    int incl = tsum;
#pragma unroll
    for (int off = 1; off < 64; off <<= 1) {
        int u = __shfl_up(incl, off);
        if (lane >= off) incl += u;
    }
    if (lane == 63) wsum[w] = incl;
    __syncthreads();
    int woff = 0;
    for (int k = 0; k < w; ++k) woff += wsum[k];
    int excl = woff + incl - tsum;
    start[i0] = excl; start[i0 + 1] = excl + c0;
    if (t == 255) start[BROWS] = excl + tsum;
    __syncthreads();
    int tot = start[BROWS];
#pragma unroll
    for (int q = 0; q < 2; ++q) {
        int r = i0 + q;
        int g = (b << BSHIFT) + r;
        if (g < NROWS_TOTAL) row_ptr[g] = ebase + start[r];
    }
    if (b == 0 && t == 0) row_ptr[NROWS_TOTAL] = TOT_E;
    if (tot <= MAXH) {
        hist[i0] = start[i0]; hist[i0 + 1] = start[i0 + 1];
        __syncthreads();
        for (int k = base + t; k < end; k += 256) {
            int2 p = staged[k];
            if (p.x < 0) continue;
            int l = atomicAdd(&hist[p.x >> 18], 1);
            ebuf[l] = make_int2(p.x & 0x3FFFF, p.y);
        }
        __syncthreads();
        for (int j = t; j < tot; j += 256) ecv[ebase + j] = ebuf[j];
    } else {
        hist[i0] = ebase + start[i0]; hist[i0 + 1] = ebase + start[i0 + 1];
        __syncthreads();
        for (int k = base + t; k < end; k += 256) {
            int2 p = staged[k];
            if (p.x < 0) continue;
            int pos = atomicAdd(&hist[p.x >> 18], 1);
            ecv[pos] = make_int2(p.x & 0x3FFFF, p.y);
        }
    }
}

// y = A x (r15 structure: 16 lanes/row, 4 rows/wave, coalesced edge load + shfl
// broadcast). Inner loop STATIC 16 (padding lanes carry v=0,c=0 -> hot dummy gather)
// so all 16 gathers issue independently.
__global__ void spmm_y(const int* __restrict__ row_ptr, const int2* __restrict__ ecv,
                       const bfu* __restrict__ x,
                       bfu* __restrict__ y, float* __restrict__ rinv, int n) {
    int t = threadIdx.x;
    int lane = t & 63;
    int sub = lane >> 4;
    int l16 = lane & 15;
    int i = blockIdx.x * 16 + (t >> 6) * 4 + sub;
    if (i >= n) return;
    int s = row_ptr[i], e = row_ptr[i + 1];
    const ushort4* x4 = (const ushort4*)x;
    float4 a = make_float4(0.f, 0.f, 0.f, 0.f);
    int gbase = sub * 16;
    for (int base = s; base < e; base += 16) {
        int idx = base + l16;
        int cl = 0; float vl = 0.0f;
        if (idx < e) { int2 p = ecv[idx]; cl = p.x; vl = __int_as_float(p.y); }
#pragma unroll
        for (int k = 0; k < 16; k += 4) {
#pragma unroll
            for (int u = 0; u < 4; ++u) {
                int c = __shfl(cl, gbase + k + u);
                float v = __shfl(vl, gbase + k + u);
                ushort4 xv = x4[(size_t)c * 16 + l16];
                a.x += v * bf2f(xv.x); a.y += v * bf2f(xv.y);
                a.z += v * bf2f(xv.z); a.w += v * bf2f(xv.w);
            }
        }
    }
    size_t o4 = (size_t)i * 16 + l16;
    ushort4 bv;
    bv.x = f2bf(a.x); bv.y = f2bf(a.y); bv.z = f2bf(a.z); bv.w = f2bf(a.w);
    ((ushort4*)y)[o4] = bv;
    float sq = a.x * a.x + a.y * a.y + a.z * a.z + a.w * a.w;
#pragma unroll
    for (int off = 8; off; off >>= 1) sq += __shfl_xor(sq, off);
    if (l16 == 0) rinv[i] = 1.0f / fmaxf(sqrtf(sq), 1e-12f);
}

// channel-2 layer 3 fused with deferred sum: mixed = u0 + r1*y1 + r2*y2 + rinv3*(A y2)
__global__ void spmm_sum(const int* __restrict__ row_ptr, const int2* __restrict__ ecv,
                         const bfu* __restrict__ x /* = y2 */,
                         const bfu* __restrict__ u0, const bfu* __restrict__ y1,
                         const float* __restrict__ r1, const float* __restrict__ r2,
                         float* __restrict__ mixed, int n) {
    int t = threadIdx.x;
    int lane = t & 63;
    int sub = lane >> 4;
    int l16 = lane & 15;
    int i = blockIdx.x * 16 + (t >> 6) * 4 + sub;
    if (i >= n) return;
    int s = row_ptr[i], e = row_ptr[i + 1];
    const ushort4* x4 = (const ushort4*)x;
    float4 a = make_float4(0.f, 0.f, 0.f, 0.f);
    int gbase = sub * 16;
    for (int base = s; base < e; base += 16) {
        int idx = base + l16;
        int cl = 0; float vl = 0.0f;
        if (idx < e) { int2 p = ecv[idx]; cl = p.x; vl = __int_as_float(p.y); }
#pragma unroll
        for (int k = 0; k < 16; k += 4) {
#pragma unroll
            for (int u = 0; u < 4; ++u) {
                int c = __shfl(cl, gbase + k + u);
                float v = __shfl(vl, gbase + k + u);
                ushort4 xv = x4[(size_t)c * 16 + l16];
                a.x += v * bf2f(xv.x); a.y += v * bf2f(xv.y);
                a.z += v * bf2f(xv.z); a.w += v * bf2f(xv.w);
            }
        }
    }
    float sq = a.x * a.x + a.y * a.y + a.z * a.z + a.w * a.w;
#pragma unroll
    for (int off = 8; off; off >>= 1) sq += __shfl_xor(sq, off);
    float r3 = 1.0f / fmaxf(sqrtf(sq), 1e-12f);
    size_t o4 = (size_t)i * 16 + l16;
    float a1 = r1[i], a2 = r2[i];
    ushort4 b0 = ((const ushort4*)u0)[o4];
    ushort4 b1 = ((const ushort4*)y1)[o4];
    ushort4 b2 = ((const ushort4*)x)[o4];
    float4 o;
    o.x = bf2f(b0.x) + a1 * bf2f(b1.x) + a2 * bf2f(b2.x) + r3 * a.x;
    o.y = bf2f(b0.y) + a1 * bf2f(b1.y) + a2 * bf2f(b2.y) + r3 * a.y;
    o.z = bf2f(b0.z) + a1 * bf2f(b1.z) + a2 * bf2f(b2.z) + r3 * a.z;
    o.w = bf2f(b0.w) + a1 * bf2f(b1.w) + a2 * bf2f(b2.w) + r3 * a.w;
    ((float4*)mixed)[o4] = o;
}

// channel-3 layer 3 fused with deferred sum + channel attention + mix
__global__ void spmm_mix(const int* __restrict__ row_ptr, const int2* __restrict__ ecv,
                         const bfu* __restrict__ x /* = y2 */,
                         const bfu* __restrict__ u0, const bfu* __restrict__ y1,
                         const float* __restrict__ r1, const float* __restrict__ r2,
                         float* __restrict__ mixed, const float* __restrict__ vvec,
                         float* __restrict__ score, int n) {
    int t = threadIdx.x;
    int lane = t & 63;
    int sub = lane >> 4;
    int l16 = lane & 15;
    int i = blockIdx.x * 16 + (t >> 6) * 4 + sub;
    if (i >= n) return;
    int s = row_ptr[i], e = row_ptr[i + 1];
    const ushort4* x4 = (const ushort4*)x;
    float4 a = make_float4(0.f, 0.f, 0.f, 0.f);
    int gbase = sub * 16;
    for (int base = s; base < e; base += 16) {
        int idx = base + l16;
        int cl = 0; float vl = 0.0f;
        if (idx < e) { int2 p = ecv[idx]; cl = p.x; vl = __int_as_float(p.y); }
#pragma unroll
        for (int k = 0; k < 16; k += 4) {
#pragma unroll
            for (int u = 0; u < 4; ++u) {
                int c = __shfl(cl, gbase + k + u);
                float v = __shfl(vl, gbase + k + u);
                ushort4 xv = x4[(size_t)c * 16 + l16];
                a.x += v * bf2f(xv.x); a.y += v * bf2f(xv.y);
                a.z += v * bf2f(xv.z); a.w += v * bf2f(xv.w);
            }
        }
    }
    float sq = a.x * a.x + a.y * a.y + a.z * a.z + a.w * a.w;
#pragma unroll
    for (int off = 8; off; off >>= 1) sq += __shfl_xor(sq, off);
    float r3 = 1.0f / fmaxf(sqrtf(sq), 1e-12f);
    size_t o4 = (size_t)i * 16 + l16;
    float a1 = r1[i], a2s = r2[i];
    ushort4 b0 = ((const ushort4*)u0)[o4];
    ushort4 b1 = ((const ushort4*)y1)[o4];
    ushort4 b2 = ((const ushort4*)x)[o4];
    float4 a3;
    a3.x = bf2f(b0.x) + a1 * bf2f(b1.x) + a2s * bf2f(b2.x) + r3 * a.x;
    a3.y = bf2f(b0.y) + a1 * bf2f(b1.y) + a2s * bf2f(b2.y) + r3 * a.y;
    a3.z = bf2f(b0.z) + a1 * bf2f(b1.z) + a2s * bf2f(b2.z) + r3 * a.z;
    a3.w = bf2f(b0.w) + a1 * bf2f(b1.w) + a2s * bf2f(b2.w) + r3 * a.w;
    float4 a2 = ((float4*)mixed)[o4];
    float4 vv = ((const float4*)vvec)[l16];
    float w2 = a2.x * vv.x + a2.y * vv.y + a2.z * vv.z + a2.w * vv.w;
    float w3 = a3.x * vv.x + a3.y * vv.y + a3.z * vv.z + a3.w * vv.w;
#pragma unroll
    for (int off = 8; off; off >>= 1) {
        w2 += __shfl_xor(w2, off);
        w3 += __shfl_xor(w3, off);
    }
    float m = fmaxf(w2, w3);
    float x2 = __expf(w2 - m), x3 = __expf(w3 - m);
    float inv = 1.0f / (x2 + x3);
    float s2 = x2 * inv, s3 = x3 * inv;
    float4 o;
    o.x = s2 * a2.x + s3 * a3.x; o.y = s2 * a2.y + s3 * a3.y;
    o.z = s2 * a2.z + s3 * a3.z; o.w = s2 * a2.w + s3 * a3.w;
    ((float4*)mixed)[o4] = o;
    if (l16 == 0) { score[(size_t)i * 2] = s2; score[(size_t)i * 2 + 1] = s3; }
}

// v[k] = sum_j att_m[k][j] * att[j]
__global__ void vvec_kernel(const float* __restrict__ att_m, const float* __restrict__ att,
                            float* __restrict__ v) {
    int k = threadIdx.x;
    float s = 0.0f;
    for (int j = 0; j < 64; ++j) s += att_m[k * 64 + j] * att[j];
    v[k] = s;
}

extern "C" void kernel_launch(void* const* d_in, const int* in_sizes, int n_in,
                              void* d_out, int out_size, void* d_ws, size_t ws_size,
                              hipStream_t stream) {
    const float* user_emb = (const float*)d_in[0];
    const float* W0 = (const float*)d_in[1];
    const float* b0 = (const float*)d_in[2];
    const float* W1 = (const float*)d_in[3];
    const float* b1 = (const float*)d_in[4];
    const float* att = (const float*)d_in[5];
    const float* att_m = (const float*)d_in[6];
    const int* item_rows = (const int*)d_in[7];
    const int* item_cols = (const int*)d_in[8];
    const float* item_vals = (const float*)d_in[9];
    const int* user_rows = (const int*)d_in[10];
    const int* user_cols = (const int*)d_in[11];
    const float* user_vals = (const float*)d_in[12];

    float* out = (float*)d_out;
    float* mixed = out;                          // N*64 fp32, holds channel-2 sum then final
    float* score = out + (size_t)N_NODE * 64;

    char* w = (char*)d_ws;
    bfu* u0 = (bfu*)w;         w += (size_t)N_NODE * 64 * 2;
    bfu* y1 = (bfu*)w;         w += (size_t)N_NODE * 64 * 2;
    bfu* y2 = (bfu*)w;         w += (size_t)N_NODE * 64 * 2;
    float* rv1 = (float*)w;    w += (size_t)N_NODE * 4;
    float* rv2 = (float*)w;    w += (size_t)N_NODE * 4;
    int* row_ptr = (int*)w;    w += ((size_t)NROWS_TOTAL + 64) * 4;
    int2* ecv = (int2*)w;      w += (size_t)TOT_E * 8;
    float* vvec = (float*)w;   w += 256;
    int* bc = (int*)w;         w += (size_t)SCAN_N * 4;
    int* soffP = (int*)w;      w += (size_t)SCAN_N * 4;
    int* bsumP = (int*)w;      w += (NBUCK + 8) * 4;
    int* btot = (int*)w;       w += (NBUCK + 8) * 4;
    int* boffP = (int*)w;      w += (NBUCK + 8) * 4;
    int* bbase = (int*)w;      w += (NBUCK + 8) * 4;
    // staged overlays u0..rv2 (78.4MB >= padded worst case 76.9MB), dead during build
    int2* staged = (int2*)u0;

    const int NB16 = (N_NODE + 15) / 16;
    const int GATE_B = (N_NODE / 16 + 15) / 16;
    const int* rp_item = row_ptr;
    const int* rp_user = row_ptr + N_NODE;

    // counting-sort CSR build, padded line-exclusive staging, LDS-sorted burst writes
    binA_kernel<<<NB, 256, 0, stream>>>(item_rows, user_rows, bc);
    scan1_kernel<<<NBUCK, 256, 0, stream>>>(bc, bsumP, btot);
    scan2_kernel<<<1, 1024, 0, stream>>>(bsumP, btot, boffP, bbase);
    scan3_kernel<<<NBUCK, 256, 0, stream>>>(bc, boffP, soffP);
    binB_kernel<<<NB, 256, 0, stream>>>(item_rows, item_cols, item_vals,
                                        user_rows, user_cols, user_vals, bc, soffP, staged);
    finalize_kernel<<<NBUCK, 256, 0, stream>>>(staged, boffP, bbase, row_ptr, ecv);
    vvec_kernel<<<1, 64, 0, stream>>>(att_m, att, vvec);

    // channel 2: item graph -> fp32 sum in mixed (layer 3 fused)
    gate_kernel<<<GATE_B, 256, 0, stream>>>(user_emb, W0, b0, u0, N_NODE);
    spmm_y<<<NB16, 256, 0, stream>>>(rp_item, ecv, u0, y1, rv1, N_NODE);
    spmm_y<<<NB16, 256, 0, stream>>>(rp_item, ecv, y1, y2, rv2, N_NODE);
    spmm_sum<<<NB16, 256, 0, stream>>>(rp_item, ecv, y2, u0, y1, rv1, rv2, mixed, N_NODE);

    // channel 3: user graph, layer 3 fused with sum + attention + mix
    gate_kernel<<<GATE_B, 256, 0, stream>>>(user_emb, W1, b1, u0, N_NODE);
    spmm_y<<<NB16, 256, 0, stream>>>(rp_user, ecv, u0, y1, rv1, N_NODE);
    spmm_y<<<NB16, 256, 0, stream>>>(rp_user, ecv, y1, y2, rv2, N_NODE);
    spmm_mix<<<NB16, 256, 0, stream>>>(rp_user, ecv, y2, u0, y1, rv1, rv2,
                                       mixed, vvec, score, N_NODE);
}

// Round 18
// 438.302 us; speedup vs baseline: 1.6384x; 1.0099x over previous
//
#include <hip/hip_runtime.h>

#define N_NODE 200000
#define EMB 64
#define N_EDGES 2000000
#define NROWS_TOTAL (2 * N_NODE)        // both graphs' rows concatenated
#define TOT_E (2 * N_EDGES)

// counting-sort geometry
#define BSHIFT 9
#define BROWS 512                                    // rows per bucket
#define NBUCK ((NROWS_TOTAL + BROWS - 1) / BROWS)    // 782
#define NB 1024                                      // binning blocks; == entries per bucket row
#define CHUNK ((TOT_E + NB - 1) / NB)                // 3907 edges per block
#define SCAN_N (NBUCK * NB)                          // 800768
#define MAXH 6144                                    // LDS edge buffer per bucket (mean ~5115)

typedef unsigned short bfu;
typedef __attribute__((ext_vector_type(8))) short bf16x8;
typedef __attribute__((ext_vector_type(4))) float f32x4;

__device__ __forceinline__ float bf2f(bfu u) { return __uint_as_float(((unsigned)u) << 16); }
__device__ __forceinline__ bfu f2bf(float f) {
    unsigned b = __float_as_uint(f);
    return (bfu)((b + 0x7FFF + ((b >> 16) & 1)) >> 16);   // RTNE, finite inputs
}
// edge pack: col (18b) << 14 | val quantized to 14-bit fixed point in [0,1); err <= 3e-5
__device__ __forceinline__ unsigned packcv(int col, float v) {
    int q = (int)(v * 16384.0f + 0.5f);
    q = q < 0 ? 0 : (q > 16383 ? 16383 : q);
    return ((unsigned)col << 14) | (unsigned)q;
}

// out = emb * sigmoid(emb @ W + b) via MFMA. Per 16-node tile: A = bf16(x rows),
// B = bf16(W) preloaded per-wave from global (L2-hot), C/D layout per m89.
__global__ void gate_kernel(const float* __restrict__ emb,
                            const float* __restrict__ W,
                            const float* __restrict__ b,
                            bfu* __restrict__ out, int n) {
    int t = threadIdx.x;
    int w = t >> 6, lane = t & 63;
    int l16 = lane & 15, kg = lane >> 4;
    bf16x8 Bf[2][4];
#pragma unroll
    for (int kb = 0; kb < 2; ++kb)
#pragma unroll
        for (int nt = 0; nt < 4; ++nt) {
            bf16x8 f;
#pragma unroll
            for (int e = 0; e < 8; ++e)
                f[e] = (short)f2bf(W[(kb * 32 + kg * 8 + e) * 64 + nt * 16 + l16]);
            Bf[kb][nt] = f;
        }
    float bias[4];
#pragma unroll
    for (int nt = 0; nt < 4; ++nt) bias[nt] = b[nt * 16 + l16];
    const float4* e4 = (const float4*)emb;
#pragma unroll 1
    for (int it = 0; it < 4; ++it) {
        int tile = blockIdx.x * 16 + w * 4 + it;
        if (tile * 16 >= n) break;
        int arow = tile * 16 + l16;
        size_t ab = (size_t)arow * 16 + kg * 2;
        float4 a0 = e4[ab], a1 = e4[ab + 1];
        float4 a2 = e4[ab + 8], a3 = e4[ab + 9];
        bf16x8 A0, A1;
        A0[0] = (short)f2bf(a0.x); A0[1] = (short)f2bf(a0.y);
        A0[2] = (short)f2bf(a0.z); A0[3] = (short)f2bf(a0.w);
        A0[4] = (short)f2bf(a1.x); A0[5] = (short)f2bf(a1.y);
        A0[6] = (short)f2bf(a1.z); A0[7] = (short)f2bf(a1.w);
        A1[0] = (short)f2bf(a2.x); A1[1] = (short)f2bf(a2.y);
        A1[2] = (short)f2bf(a2.z); A1[3] = (short)f2bf(a2.w);
        A1[4] = (short)f2bf(a3.x); A1[5] = (short)f2bf(a3.y);
        A1[6] = (short)f2bf(a3.z); A1[7] = (short)f2bf(a3.w);
        f32x4 acc[4];
#pragma unroll
        for (int nt = 0; nt < 4; ++nt) {
            acc[nt] = (f32x4){0.f, 0.f, 0.f, 0.f};
            acc[nt] = __builtin_amdgcn_mfma_f32_16x16x32_bf16(A0, Bf[0][nt], acc[nt], 0, 0, 0);
            acc[nt] = __builtin_amdgcn_mfma_f32_16x16x32_bf16(A1, Bf[1][nt], acc[nt], 0, 0, 0);
        }
#pragma unroll
        for (int nt = 0; nt < 4; ++nt) {
#pragma unroll
            for (int r = 0; r < 4; ++r) {
                int orow = tile * 16 + kg * 4 + r;
                int col = nt * 16 + l16;
                float s = acc[nt][r] + bias[nt];
                float g = 1.0f / (1.0f + __expf(-s));
                float xv = emb[(size_t)orow * 64 + col];
                out[(size_t)orow * 64 + col] = f2bf(xv * g);
            }
        }
    }
}

// phase 1: per-block LDS bucket histogram -> bc[bucket*NB + blk]
__global__ void binA_kernel(const int* __restrict__ item_rows,
                            const int* __restrict__ user_rows,
                            int* __restrict__ bc) {
    __shared__ int h[NBUCK];
    int t = threadIdx.x, blk = blockIdx.x;
    for (int k = t; k < NBUCK; k += 256) h[k] = 0;
    __syncthreads();
    int lo = blk * CHUNK, hi = min(lo + CHUNK, TOT_E);
    for (int i = lo + t; i < hi; i += 256) {
        int g = (i < N_EDGES) ? item_rows[i] : (N_NODE + user_rows[i - N_EDGES]);
        atomicAdd(&h[g >> BSHIFT], 1);
    }
    __syncthreads();
    for (int k = t; k < NBUCK; k += 256) bc[k * NB + blk] = h[k];
}

// scan1: one block per bucket (NB==1024 entries). Outputs padded bucket total + real bucket total.
__global__ void scan1_kernel(const int* __restrict__ bc, int* __restrict__ bsumP,
                             int* __restrict__ btot) {
    int b = blockIdx.x, t = threadIdx.x;
    int base = b * NB + t * 4;
    int sR = 0, sP = 0;
#pragma unroll
    for (int k = 0; k < 4; ++k) {
        int c = bc[base + k];
        sR += c;
        sP += (c + 7) & ~7;
    }
#pragma unroll
    for (int off = 32; off; off >>= 1) {
        sR += __shfl_xor(sR, off);
        sP += __shfl_xor(sP, off);
    }
    __shared__ int wsR[4], wsP[4];
    int lane = t & 63, w = t >> 6;
    if (lane == 0) { wsR[w] = sR; wsP[w] = sP; }
    __syncthreads();
    if (t == 0) {
        btot[b] = wsR[0] + wsR[1] + wsR[2] + wsR[3];
        bsumP[b] = wsP[0] + wsP[1] + wsP[2] + wsP[3];
    }
}

// scan2: dual exclusive scan over NBUCK entries (1024 threads)
__global__ void scan2_kernel(const int* __restrict__ bsumP, const int* __restrict__ btot,
                             int* __restrict__ boffP, int* __restrict__ bbase) {
    __shared__ int sh[1024];
    int t = threadIdx.x;
    int vP = (t < NBUCK) ? bsumP[t] : 0;
    sh[t] = vP;
    __syncthreads();
    for (int off = 1; off < 1024; off <<= 1) {
        int u = (t >= off) ? sh[t - off] : 0;
        __syncthreads();
        sh[t] += u;
        __syncthreads();
    }
    if (t < NBUCK) boffP[t] = sh[t] - vP;
    if (t == 1023) boffP[NBUCK] = sh[1023];
    __syncthreads();
    int vR = (t < NBUCK) ? btot[t] : 0;
    sh[t] = vR;
    __syncthreads();
    for (int off = 1; off < 1024; off <<= 1) {
        int u = (t >= off) ? sh[t - off] : 0;
        __syncthreads();
        sh[t] += u;
        __syncthreads();
    }
    if (t < NBUCK) bbase[t] = sh[t] - vR;
}

// scan3: per-entry PADDED exclusive offsets within bucket, based at boffP[bucket]
__global__ void scan3_kernel(const int* __restrict__ bc, const int* __restrict__ boffP,
                             int* __restrict__ soffP) {
    int b = blockIdx.x, t = threadIdx.x;
    int lane = t & 63, w = t >> 6;
    int base = b * NB + t * 4;
    int p[4];
#pragma unroll
    for (int k = 0; k < 4; ++k) p[k] = (bc[base + k] + 7) & ~7;
    int e1 = p[0], e2 = p[0] + p[1], e3 = p[0] + p[1] + p[2];
    int tsum = e3 + p[3];
    int incl = tsum;
#pragma unroll
    for (int off = 1; off < 64; off <<= 1) {
        int u = __shfl_up(incl, off);
        if (lane >= off) incl += u;
    }
    int excl = incl - tsum;
    __shared__ int wsum[4];
    if (lane == 63) wsum[w] = incl;
    __syncthreads();
    int woff = 0;
    for (int k = 0; k < 4; ++k) if (k < w) woff += wsum[k];
    int g = boffP[b] + woff + excl;
    soffP[base + 0] = g;
    soffP[base + 1] = g + e1;
    soffP[base + 2] = g + e2;
    soffP[base + 3] = g + e3;
}

// phase 2: LDS counting sort + burst write. Histogram comes FREE from bc.
__global__ void binB_kernel(const int* __restrict__ item_rows, const int* __restrict__ item_cols,
                            const float* __restrict__ item_vals,
                            const int* __restrict__ user_rows, const int* __restrict__ user_cols,
                            const float* __restrict__ user_vals,
                            const int* __restrict__ bc, const int* __restrict__ soffP,
                            int2* __restrict__ staged) {
    __shared__ int2 ebuf[CHUNK];         // bucket-sorted edges (31.3 KB)
    __shared__ unsigned short sbk[CHUNK];// slot -> bucket (7.8 KB)
    __shared__ int lbase[NBUCK + 1];
    __shared__ int lcur[NBUCK];
    __shared__ int gb[NBUCK];
    __shared__ int wsum[4];
    int t = threadIdx.x, blk = blockIdx.x;
    for (int k = t; k < NBUCK; k += 256) gb[k] = soffP[k * NB + blk];
    {
        int i0 = t * 4;
        int p0 = (i0 < NBUCK) ? bc[i0 * NB + blk] : 0;
        int p1 = (i0 + 1 < NBUCK) ? bc[(i0 + 1) * NB + blk] : 0;
        int p2 = (i0 + 2 < NBUCK) ? bc[(i0 + 2) * NB + blk] : 0;
        int p3 = (i0 + 3 < NBUCK) ? bc[(i0 + 3) * NB + blk] : 0;
        int tsum = p0 + p1 + p2 + p3;
        int lane = t & 63, w = t >> 6;
        int incl = tsum;
#pragma unroll
        for (int off = 1; off < 64; off <<= 1) {
            int u = __shfl_up(incl, off);
            if (lane >= off) incl += u;
        }
        if (lane == 63) wsum[w] = incl;
        __syncthreads();
        int woff = 0;
        for (int k = 0; k < w; ++k) woff += wsum[k];
        int excl = woff + incl - tsum;
        if (i0 < NBUCK) { lbase[i0] = excl; lcur[i0] = excl; }
        if (i0 + 1 < NBUCK) { lbase[i0 + 1] = excl + p0; lcur[i0 + 1] = excl + p0; }
        if (i0 + 2 < NBUCK) { lbase[i0 + 2] = excl + p0 + p1; lcur[i0 + 2] = excl + p0 + p1; }
        if (i0 + 3 < NBUCK) { lbase[i0 + 3] = excl + p0 + p1 + p2; lcur[i0 + 3] = excl + p0 + p1 + p2; }
        if (t == 255) lbase[NBUCK] = excl + tsum;   // == edges in this chunk
    }
    __syncthreads();
    int lo = blk * CHUNK, hi = min(lo + CHUNK, TOT_E);
    int cnt = hi - lo;
    for (int i = lo + t; i < hi; i += 256) {
        int g, c; float v;
        if (i < N_EDGES) { g = item_rows[i]; c = item_cols[i]; v = item_vals[i]; }
        else { int j = i - N_EDGES; g = N_NODE + user_rows[j]; c = user_cols[j]; v = user_vals[j]; }
        int bk = g >> BSHIFT;
        int s = atomicAdd(&lcur[bk], 1);
        ebuf[s] = make_int2(((g & (BROWS - 1)) << 18) | c, __float_as_int(v));
        sbk[s] = (unsigned short)bk;
    }
    __syncthreads();
    for (int j = t; j < cnt; j += 256) {
        int k = sbk[j];
        staged[gb[k] + (j - lbase[k])] = ebuf[j];
    }
    for (int k = t; k < NBUCK; k += 256) {
        int c = lbase[k + 1] - lbase[k];
        int s = gb[k] + c, e = gb[k] + ((c + 7) & ~7);
        for (int q = s; q < e; ++q) staged[q] = make_int2(-1, 0);
    }
}

// phase 3: one WG per 512-row bucket; writes PACKED 4B edges into ecv.
__global__ void finalize_kernel(const int2* __restrict__ staged, const int* __restrict__ boffP,
                                const int* __restrict__ bbase,
                                int* __restrict__ row_ptr, unsigned* __restrict__ ecv) {
    __shared__ int hist[BROWS];
    __shared__ int start[BROWS + 1];
    __shared__ int2 ebuf[MAXH];
    __shared__ int wsum[4];
    int b = blockIdx.x, t = threadIdx.x;
    int base = boffP[b], end = boffP[b + 1];
    int ebase = bbase[b];
    hist[t * 2] = 0; hist[t * 2 + 1] = 0;
    __syncthreads();
    for (int k = base + t; k < end; k += 256) {
        int gx = staged[k].x;
        if (gx >= 0) atomicAdd(&hist[gx >> 18], 1);
    }
    __syncthreads();
    int i0 = t * 2;
    int c0 = hist[i0], c1 = hist[i0 + 1];
    int tsum = c0 + c1;
    int lane = t & 63, w = t >> 6;
    int incl = tsum;
#pragma unroll
    for (int off = 1; off < 64; off <<= 1) {
        int u = __shfl_up(incl, off);
        if (lane >= off) incl += u;
    }
    if (lane == 63) wsum[w] = incl;
    __syncthreads();
    int woff = 0;
    for (int k = 0; k < w; ++k) woff += wsum[k];
    int excl = woff + incl - tsum;
    start[i0] = excl; start[i0 + 1] = excl + c0;
    if (t == 255) start[BROWS] = excl + tsum;
    __syncthreads();
    int tot = start[BROWS];
#pragma unroll
    for (int q = 0; q < 2; ++q) {
        int r = i0 + q;
        int g = (b << BSHIFT) + r;
        if (g < NROWS_TOTAL) row_ptr[g] = ebase + start[r];
    }
    if (b == 0 && t == 0) row_ptr[NROWS_TOTAL] = TOT_E;
    if (tot <= MAXH) {
        hist[i0] = start[i0]; hist[i0 + 1] = start[i0 + 1];
        __syncthreads();
        for (int k = base + t; k < end; k += 256) {
            int2 p = staged[k];
            if (p.x < 0) continue;
            int l = atomicAdd(&hist[p.x >> 18], 1);
            ebuf[l] = make_int2(p.x & 0x3FFFF, p.y);
        }
        __syncthreads();
        for (int j = t; j < tot; j += 256) {
            int2 q = ebuf[j];
            ecv[ebase + j] = packcv(q.x, __int_as_float(q.y));
        }
    } else {
        hist[i0] = ebase + start[i0]; hist[i0 + 1] = ebase + start[i0 + 1];
        __syncthreads();
        for (int k = base + t; k < end; k += 256) {
            int2 p = staged[k];
            if (p.x < 0) continue;
            int pos = atomicAdd(&hist[p.x >> 18], 1);
            ecv[pos] = packcv(p.x & 0x3FFFF, __int_as_float(p.y));
        }
    }
}

// y = A x (r15 structure: 16 lanes/row, 4 rows/wave, coalesced PACKED edge load +
// shfl broadcast, dynamic unroll-4 groups of independent gathers).
__global__ void spmm_y(const int* __restrict__ row_ptr, const unsigned* __restrict__ ecv,
                       const bfu* __restrict__ x,
                       bfu* __restrict__ y, float* __restrict__ rinv, int n) {
    int t = threadIdx.x;
    int lane = t & 63;
    int sub = lane >> 4;
    int l16 = lane & 15;
    int i = blockIdx.x * 16 + (t >> 6) * 4 + sub;
    if (i >= n) return;
    int s = row_ptr[i], e = row_ptr[i + 1];
    const ushort4* x4 = (const ushort4*)x;
    float4 a = make_float4(0.f, 0.f, 0.f, 0.f);
    int gbase = sub * 16;
    for (int base = s; base < e; base += 16) {
        int idx = base + l16;
        unsigned pl = 0;
        if (idx < e) pl = ecv[idx];
        int cnt = min(16, e - base);
        int cnt4 = (cnt + 3) & ~3;
        for (int k = 0; k < cnt4; k += 4) {
#pragma unroll
            for (int u = 0; u < 4; ++u) {
                unsigned p = (unsigned)__shfl((int)pl, gbase + k + u);
                int c = p >> 14;
                float v = (float)(p & 16383u) * (1.0f / 16384.0f);
                ushort4 xv = x4[(size_t)c * 16 + l16];
                a.x += v * bf2f(xv.x); a.y += v * bf2f(xv.y);
                a.z += v * bf2f(xv.z); a.w += v * bf2f(xv.w);
            }
        }
    }
    size_t o4 = (size_t)i * 16 + l16;
    ushort4 bv;
    bv.x = f2bf(a.x); bv.y = f2bf(a.y); bv.z = f2bf(a.z); bv.w = f2bf(a.w);
    ((ushort4*)y)[o4] = bv;
    float sq = a.x * a.x + a.y * a.y + a.z * a.z + a.w * a.w;
#pragma unroll
    for (int off = 8; off; off >>= 1) sq += __shfl_xor(sq, off);
    if (l16 == 0) rinv[i] = 1.0f / fmaxf(sqrtf(sq), 1e-12f);
}

// channel-2 layer 3 fused with deferred sum: mixed = u0 + r1*y1 + r2*y2 + rinv3*(A y2)
__global__ void spmm_sum(const int* __restrict__ row_ptr, const unsigned* __restrict__ ecv,
                         const bfu* __restrict__ x /* = y2 */,
                         const bfu* __restrict__ u0, const bfu* __restrict__ y1,
                         const float* __restrict__ r1, const float* __restrict__ r2,
                         float* __restrict__ mixed, int n) {
    int t = threadIdx.x;
    int lane = t & 63;
    int sub = lane >> 4;
    int l16 = lane & 15;
    int i = blockIdx.x * 16 + (t >> 6) * 4 + sub;
    if (i >= n) return;
    int s = row_ptr[i], e = row_ptr[i + 1];
    const ushort4* x4 = (const ushort4*)x;
    float4 a = make_float4(0.f, 0.f, 0.f, 0.f);
    int gbase = sub * 16;
    for (int base = s; base < e; base += 16) {
        int idx = base + l16;
        unsigned pl = 0;
        if (idx < e) pl = ecv[idx];
        int cnt = min(16, e - base);
        int cnt4 = (cnt + 3) & ~3;
        for (int k = 0; k < cnt4; k += 4) {
#pragma unroll
            for (int u = 0; u < 4; ++u) {
                unsigned p = (unsigned)__shfl((int)pl, gbase + k + u);
                int c = p >> 14;
                float v = (float)(p & 16383u) * (1.0f / 16384.0f);
                ushort4 xv = x4[(size_t)c * 16 + l16];
                a.x += v * bf2f(xv.x); a.y += v * bf2f(xv.y);
                a.z += v * bf2f(xv.z); a.w += v * bf2f(xv.w);
            }
        }
    }
    float sq = a.x * a.x + a.y * a.y + a.z * a.z + a.w * a.w;
#pragma unroll
    for (int off = 8; off; off >>= 1) sq += __shfl_xor(sq, off);
    float r3 = 1.0f / fmaxf(sqrtf(sq), 1e-12f);
    size_t o4 = (size_t)i * 16 + l16;
    float a1 = r1[i], a2 = r2[i];
    ushort4 b0 = ((const ushort4*)u0)[o4];
    ushort4 b1 = ((const ushort4*)y1)[o4];
    ushort4 b2 = ((const ushort4*)x)[o4];
    float4 o;
    o.x = bf2f(b0.x) + a1 * bf2f(b1.x) + a2 * bf2f(b2.x) + r3 * a.x;
    o.y = bf2f(b0.y) + a1 * bf2f(b1.y) + a2 * bf2f(b2.y) + r3 * a.y;
    o.z = bf2f(b0.z) + a1 * bf2f(b1.z) + a2 * bf2f(b2.z) + r3 * a.z;
    o.w = bf2f(b0.w) + a1 * bf2f(b1.w) + a2 * bf2f(b2.w) + r3 * a.w;
    ((float4*)mixed)[o4] = o;
}

// channel-3 layer 3 fused with deferred sum + channel attention + mix
__global__ void spmm_mix(const int* __restrict__ row_ptr, const unsigned* __restrict__ ecv,
                         const bfu* __restrict__ x /* = y2 */,
                         const bfu* __restrict__ u0, const bfu* __restrict__ y1,
                         const float* __restrict__ r1, const float* __restrict__ r2,
                         float* __restrict__ mixed, const float* __restrict__ vvec,
                         float* __restrict__ score, int n) {
    int t = threadIdx.x;
    int lane = t & 63;
    int sub = lane >> 4;
    int l16 = lane & 15;
    int i = blockIdx.x * 16 + (t >> 6) * 4 + sub;
    if (i >= n) return;
    int s = row_ptr[i], e = row_ptr[i + 1];
    const ushort4* x4 = (const ushort4*)x;
    float4 a = make_float4(0.f, 0.f, 0.f, 0.f);
    int gbase = sub * 16;
    for (int base = s; base < e; base += 16) {
        int idx = base + l16;
        unsigned pl = 0;
        if (idx < e) pl = ecv[idx];
        int cnt = min(16, e - base);
        int cnt4 = (cnt + 3) & ~3;
        for (int k = 0; k < cnt4; k += 4) {
#pragma unroll
            for (int u = 0; u < 4; ++u) {
                unsigned p = (unsigned)__shfl((int)pl, gbase + k + u);
                int c = p >> 14;
                float v = (float)(p & 16383u) * (1.0f / 16384.0f);
                ushort4 xv = x4[(size_t)c * 16 + l16];
                a.x += v * bf2f(xv.x); a.y += v * bf2f(xv.y);
                a.z += v * bf2f(xv.z); a.w += v * bf2f(xv.w);
            }
        }
    }
    float sq = a.x * a.x + a.y * a.y + a.z * a.z + a.w * a.w;
#pragma unroll
    for (int off = 8; off; off >>= 1) sq += __shfl_xor(sq, off);
    float r3 = 1.0f / fmaxf(sqrtf(sq), 1e-12f);
    size_t o4 = (size_t)i * 16 + l16;
    float a1 = r1[i], a2s = r2[i];
    ushort4 b0 = ((const ushort4*)u0)[o4];
    ushort4 b1 = ((const ushort4*)y1)[o4];
    ushort4 b2 = ((const ushort4*)x)[o4];
    float4 a3;
    a3.x = bf2f(b0.x) + a1 * bf2f(b1.x) + a2s * bf2f(b2.x) + r3 * a.x;
    a3.y = bf2f(b0.y) + a1 * bf2f(b1.y) + a2s * bf2f(b2.y) + r3 * a.y;
    a3.z = bf2f(b0.z) + a1 * bf2f(b1.z) + a2s * bf2f(b2.z) + r3 * a.z;
    a3.w = bf2f(b0.w) + a1 * bf2f(b1.w) + a2s * bf2f(b2.w) + r3 * a.w;
    float4 a2 = ((float4*)mixed)[o4];
    float4 vv = ((const float4*)vvec)[l16];
    float w2 = a2.x * vv.x + a2.y * vv.y + a2.z * vv.z + a2.w * vv.w;
    float w3 = a3.x * vv.x + a3.y * vv.y + a3.z * vv.z + a3.w * vv.w;
#pragma unroll
    for (int off = 8; off; off >>= 1) {
        w2 += __shfl_xor(w2, off);
        w3 += __shfl_xor(w3, off);
    }
    float m = fmaxf(w2, w3);
    float x2 = __expf(w2 - m), x3 = __expf(w3 - m);
    float inv = 1.0f / (x2 + x3);
    float s2 = x2 * inv, s3 = x3 * inv;
    float4 o;
    o.x = s2 * a2.x + s3 * a3.x; o.y = s2 * a2.y + s3 * a3.y;
    o.z = s2 * a2.z + s3 * a3.z; o.w = s2 * a2.w + s3 * a3.w;
    ((float4*)mixed)[o4] = o;
    if (l16 == 0) { score[(size_t)i * 2] = s2; score[(size_t)i * 2 + 1] = s3; }
}

// v[k] = sum_j att_m[k][j] * att[j]
__global__ void vvec_kernel(const float* __restrict__ att_m, const float* __restrict__ att,
                            float* __restrict__ v) {
    int k = threadIdx.x;
    float s = 0.0f;
    for (int j = 0; j < 64; ++j) s += att_m[k * 64 + j] * att[j];
    v[k] = s;
}

extern "C" void kernel_launch(void* const* d_in, const int* in_sizes, int n_in,
                              void* d_out, int out_size, void* d_ws, size_t ws_size,
                              hipStream_t stream) {
    const float* user_emb = (const float*)d_in[0];
    const float* W0 = (const float*)d_in[1];
    const float* b0 = (const float*)d_in[2];
    const float* W1 = (const float*)d_in[3];
    const float* b1 = (const float*)d_in[4];
    const float* att = (const float*)d_in[5];
    const float* att_m = (const float*)d_in[6];
    const int* item_rows = (const int*)d_in[7];
    const int* item_cols = (const int*)d_in[8];
    const float* item_vals = (const float*)d_in[9];
    const int* user_rows = (const int*)d_in[10];
    const int* user_cols = (const int*)d_in[11];
    const float* user_vals = (const float*)d_in[12];

    float* out = (float*)d_out;
    float* mixed = out;                          // N*64 fp32, holds channel-2 sum then final
    float* score = out + (size_t)N_NODE * 64;

    char* w = (char*)d_ws;
    bfu* u0 = (bfu*)w;         w += (size_t)N_NODE * 64 * 2;
    bfu* y1 = (bfu*)w;         w += (size_t)N_NODE * 64 * 2;
    bfu* y2 = (bfu*)w;         w += (size_t)N_NODE * 64 * 2;
    float* rv1 = (float*)w;    w += (size_t)N_NODE * 4;
    float* rv2 = (float*)w;    w += (size_t)N_NODE * 4;
    int* row_ptr = (int*)w;    w += ((size_t)NROWS_TOTAL + 64) * 4;
    unsigned* ecv = (unsigned*)w; w += (size_t)TOT_E * 4;
    float* vvec = (float*)w;   w += 256;
    int* bc = (int*)w;         w += (size_t)SCAN_N * 4;
    int* soffP = (int*)w;      w += (size_t)SCAN_N * 4;
    int* bsumP = (int*)w;      w += (NBUCK + 8) * 4;
    int* btot = (int*)w;       w += (NBUCK + 8) * 4;
    int* boffP = (int*)w;      w += (NBUCK + 8) * 4;
    int* bbase = (int*)w;      w += (NBUCK + 8) * 4;
    // staged overlays u0..rv2 (78.4MB >= padded worst case 76.9MB), dead during build
    int2* staged = (int2*)u0;

    const int NB16 = (N_NODE + 15) / 16;
    const int GATE_B = (N_NODE / 16 + 15) / 16;
    const int* rp_item = row_ptr;
    const int* rp_user = row_ptr + N_NODE;

    // counting-sort CSR build, padded line-exclusive staging, LDS-sorted burst writes
    binA_kernel<<<NB, 256, 0, stream>>>(item_rows, user_rows, bc);
    scan1_kernel<<<NBUCK, 256, 0, stream>>>(bc, bsumP, btot);
    scan2_kernel<<<1, 1024, 0, stream>>>(bsumP, btot, boffP, bbase);
    scan3_kernel<<<NBUCK, 256, 0, stream>>>(bc, boffP, soffP);
    binB_kernel<<<NB, 256, 0, stream>>>(item_rows, item_cols, item_vals,
                                        user_rows, user_cols, user_vals, bc, soffP, staged);
    finalize_kernel<<<NBUCK, 256, 0, stream>>>(staged, boffP, bbase, row_ptr, ecv);
    vvec_kernel<<<1, 64, 0, stream>>>(att_m, att, vvec);

    // channel 2: item graph -> fp32 sum in mixed (layer 3 fused)
    gate_kernel<<<GATE_B, 256, 0, stream>>>(user_emb, W0, b0, u0, N_NODE);
    spmm_y<<<NB16, 256, 0, stream>>>(rp_item, ecv, u0, y1, rv1, N_NODE);
    spmm_y<<<NB16, 256, 0, stream>>>(rp_item, ecv, y1, y2, rv2, N_NODE);
    spmm_sum<<<NB16, 256, 0, stream>>>(rp_item, ecv, y2, u0, y1, rv1, rv2, mixed, N_NODE);

    // channel 3: user graph, layer 3 fused with sum + attention + mix
    gate_kernel<<<GATE_B, 256, 0, stream>>>(user_emb, W1, b1, u0, N_NODE);
    spmm_y<<<NB16, 256, 0, stream>>>(rp_user, ecv, u0, y1, rv1, N_NODE);
    spmm_y<<<NB16, 256, 0, stream>>>(rp_user, ecv, y1, y2, rv2, N_NODE);
    spmm_mix<<<NB16, 256, 0, stream>>>(rp_user, ecv, y2, u0, y1, rv1, rv2,
                                       mixed, vvec, score, N_NODE);
}

// Round 19
// 419.169 us; speedup vs baseline: 1.7132x; 1.0456x over previous
//
#include <hip/hip_runtime.h>

#define N_NODE 200000
#define EMB 64
#define N_EDGES 2000000
#define NROWS_TOTAL (2 * N_NODE)        // both graphs' rows concatenated
#define TOT_E (2 * N_EDGES)

// counting-sort geometry
#define BSHIFT 9
#define BROWS 512                                    // rows per bucket
#define NBUCK ((NROWS_TOTAL + BROWS - 1) / BROWS)    // 782
#define NB 1024                                      // binning blocks; == entries per bucket row
#define CHUNK ((TOT_E + NB - 1) / NB)                // 3907 edges per block
#define SCAN_N (NBUCK * NB)                          // 800768
#define MAXH 6144                                    // LDS edge buffer per bucket (mean ~5115)
#define GATE_B ((N_NODE / 16 + 15) / 16)             // 782 blocks per channel half

typedef unsigned short bfu;
typedef __attribute__((ext_vector_type(8))) short bf16x8;
typedef __attribute__((ext_vector_type(4))) float f32x4;

__device__ __forceinline__ float bf2f(bfu u) { return __uint_as_float(((unsigned)u) << 16); }
__device__ __forceinline__ bfu f2bf(float f) {
    unsigned b = __float_as_uint(f);
    return (bfu)((b + 0x7FFF + ((b >> 16) & 1)) >> 16);   // RTNE, finite inputs
}
// edge pack: col (18b) << 14 | val quantized to 14-bit fixed point in [0,1); err <= 3e-5
__device__ __forceinline__ unsigned packcv(int col, float v) {
    int q = (int)(v * 16384.0f + 0.5f);
    q = q < 0 ? 0 : (q > 16383 ? 16383 : q);
    return ((unsigned)col << 14) | (unsigned)q;
}

// Both channels' gating in one dispatch: half 0 -> W0/b0 -> u0[0..N), half 1 -> W1/b1 -> u0[N..2N)
__global__ void gate2_kernel(const float* __restrict__ emb,
                             const float* __restrict__ W0, const float* __restrict__ b0,
                             const float* __restrict__ W1, const float* __restrict__ b1,
                             bfu* __restrict__ out) {
    int blk = blockIdx.x;
    int half = (blk >= GATE_B) ? 1 : 0;
    const float* W = half ? W1 : W0;
    const float* b = half ? b1 : b0;
    bfu* o = out + (size_t)half * N_NODE * 64;
    int bblk = blk - half * GATE_B;
    int t = threadIdx.x;
    int w = t >> 6, lane = t & 63;
    int l16 = lane & 15, kg = lane >> 4;
    bf16x8 Bf[2][4];
#pragma unroll
    for (int kb = 0; kb < 2; ++kb)
#pragma unroll
        for (int nt = 0; nt < 4; ++nt) {
            bf16x8 f;
#pragma unroll
            for (int e = 0; e < 8; ++e)
                f[e] = (short)f2bf(W[(kb * 32 + kg * 8 + e) * 64 + nt * 16 + l16]);
            Bf[kb][nt] = f;
        }
    float bias[4];
#pragma unroll
    for (int nt = 0; nt < 4; ++nt) bias[nt] = b[nt * 16 + l16];
    const float4* e4 = (const float4*)emb;
#pragma unroll 1
    for (int it = 0; it < 4; ++it) {
        int tile = bblk * 16 + w * 4 + it;
        if (tile * 16 >= N_NODE) break;
        int arow = tile * 16 + l16;
        size_t ab = (size_t)arow * 16 + kg * 2;
        float4 a0 = e4[ab], a1 = e4[ab + 1];
        float4 a2 = e4[ab + 8], a3 = e4[ab + 9];
        bf16x8 A0, A1;
        A0[0] = (short)f2bf(a0.x); A0[1] = (short)f2bf(a0.y);
        A0[2] = (short)f2bf(a0.z); A0[3] = (short)f2bf(a0.w);
        A0[4] = (short)f2bf(a1.x); A0[5] = (short)f2bf(a1.y);
        A0[6] = (short)f2bf(a1.z); A0[7] = (short)f2bf(a1.w);
        A1[0] = (short)f2bf(a2.x); A1[1] = (short)f2bf(a2.y);
        A1[2] = (short)f2bf(a2.z); A1[3] = (short)f2bf(a2.w);
        A1[4] = (short)f2bf(a3.x); A1[5] = (short)f2bf(a3.y);
        A1[6] = (short)f2bf(a3.z); A1[7] = (short)f2bf(a3.w);
        f32x4 acc[4];
#pragma unroll
        for (int nt = 0; nt < 4; ++nt) {
            acc[nt] = (f32x4){0.f, 0.f, 0.f, 0.f};
            acc[nt] = __builtin_amdgcn_mfma_f32_16x16x32_bf16(A0, Bf[0][nt], acc[nt], 0, 0, 0);
            acc[nt] = __builtin_amdgcn_mfma_f32_16x16x32_bf16(A1, Bf[1][nt], acc[nt], 0, 0, 0);
        }
#pragma unroll
        for (int nt = 0; nt < 4; ++nt) {
#pragma unroll
            for (int r = 0; r < 4; ++r) {
                int orow = tile * 16 + kg * 4 + r;
                int col = nt * 16 + l16;
                float s = acc[nt][r] + bias[nt];
                float g = 1.0f / (1.0f + __expf(-s));
                float xv = emb[(size_t)orow * 64 + col];
                o[(size_t)orow * 64 + col] = f2bf(xv * g);
            }
        }
    }
}

// phase 1: per-block LDS bucket histogram -> bc[bucket*NB + blk]
__global__ void binA_kernel(const int* __restrict__ item_rows,
                            const int* __restrict__ user_rows,
                            int* __restrict__ bc) {
    __shared__ int h[NBUCK];
    int t = threadIdx.x, blk = blockIdx.x;
    for (int k = t; k < NBUCK; k += 256) h[k] = 0;
    __syncthreads();
    int lo = blk * CHUNK, hi = min(lo + CHUNK, TOT_E);
    for (int i = lo + t; i < hi; i += 256) {
        int g = (i < N_EDGES) ? item_rows[i] : (N_NODE + user_rows[i - N_EDGES]);
        atomicAdd(&h[g >> BSHIFT], 1);
    }
    __syncthreads();
    for (int k = t; k < NBUCK; k += 256) bc[k * NB + blk] = h[k];
}

// scan1: one block per bucket (NB==1024 entries). Outputs padded bucket total + real bucket total.
__global__ void scan1_kernel(const int* __restrict__ bc, int* __restrict__ bsumP,
                             int* __restrict__ btot) {
    int b = blockIdx.x, t = threadIdx.x;
    int base = b * NB + t * 4;
    int sR = 0, sP = 0;
#pragma unroll
    for (int k = 0; k < 4; ++k) {
        int c = bc[base + k];
        sR += c;
        sP += (c + 7) & ~7;
    }
#pragma unroll
    for (int off = 32; off; off >>= 1) {
        sR += __shfl_xor(sR, off);
        sP += __shfl_xor(sP, off);
    }
    __shared__ int wsR[4], wsP[4];
    int lane = t & 63, w = t >> 6;
    if (lane == 0) { wsR[w] = sR; wsP[w] = sP; }
    __syncthreads();
    if (t == 0) {
        btot[b] = wsR[0] + wsR[1] + wsR[2] + wsR[3];
        bsumP[b] = wsP[0] + wsP[1] + wsP[2] + wsP[3];
    }
}

// scan2: dual exclusive scan over NBUCK entries (1024 threads)
__global__ void scan2_kernel(const int* __restrict__ bsumP, const int* __restrict__ btot,
                             int* __restrict__ boffP, int* __restrict__ bbase) {
    __shared__ int sh[1024];
    int t = threadIdx.x;
    int vP = (t < NBUCK) ? bsumP[t] : 0;
    sh[t] = vP;
    __syncthreads();
    for (int off = 1; off < 1024; off <<= 1) {
        int u = (t >= off) ? sh[t - off] : 0;
        __syncthreads();
        sh[t] += u;
        __syncthreads();
    }
    if (t < NBUCK) boffP[t] = sh[t] - vP;
    if (t == 1023) boffP[NBUCK] = sh[1023];
    __syncthreads();
    int vR = (t < NBUCK) ? btot[t] : 0;
    sh[t] = vR;
    __syncthreads();
    for (int off = 1; off < 1024; off <<= 1) {
        int u = (t >= off) ? sh[t - off] : 0;
        __syncthreads();
        sh[t] += u;
        __syncthreads();
    }
    if (t < NBUCK) bbase[t] = sh[t] - vR;
}

// scan3: per-entry PADDED exclusive offsets within bucket, based at boffP[bucket]
__global__ void scan3_kernel(const int* __restrict__ bc, const int* __restrict__ boffP,
                             int* __restrict__ soffP) {
    int b = blockIdx.x, t = threadIdx.x;
    int lane = t & 63, w = t >> 6;
    int base = b * NB + t * 4;
    int p[4];
#pragma unroll
    for (int k = 0; k < 4; ++k) p[k] = (bc[base + k] + 7) & ~7;
    int e1 = p[0], e2 = p[0] + p[1], e3 = p[0] + p[1] + p[2];
    int tsum = e3 + p[3];
    int incl = tsum;
#pragma unroll
    for (int off = 1; off < 64; off <<= 1) {
        int u = __shfl_up(incl, off);
        if (lane >= off) incl += u;
    }
    int excl = incl - tsum;
    __shared__ int wsum[4];
    if (lane == 63) wsum[w] = incl;
    __syncthreads();
    int woff = 0;
    for (int k = 0; k < 4; ++k) if (k < w) woff += wsum[k];
    int g = boffP[b] + woff + excl;
    soffP[base + 0] = g;
    soffP[base + 1] = g + e1;
    soffP[base + 2] = g + e2;
    soffP[base + 3] = g + e3;
}

// phase 2: LDS counting sort + burst write. Histogram comes FREE from bc.
__global__ void binB_kernel(const int* __restrict__ item_rows, const int* __restrict__ item_cols,
                            const float* __restrict__ item_vals,
                            const int* __restrict__ user_rows, const int* __restrict__ user_cols,
                            const float* __restrict__ user_vals,
                            const int* __restrict__ bc, const int* __restrict__ soffP,
                            int2* __restrict__ staged) {
    __shared__ int2 ebuf[CHUNK];
    __shared__ unsigned short sbk[CHUNK];
    __shared__ int lbase[NBUCK + 1];
    __shared__ int lcur[NBUCK];
    __shared__ int gb[NBUCK];
    __shared__ int wsum[4];
    int t = threadIdx.x, blk = blockIdx.x;
    for (int k = t; k < NBUCK; k += 256) gb[k] = soffP[k * NB + blk];
    {
        int i0 = t * 4;
        int p0 = (i0 < NBUCK) ? bc[i0 * NB + blk] : 0;
        int p1 = (i0 + 1 < NBUCK) ? bc[(i0 + 1) * NB + blk] : 0;
        int p2 = (i0 + 2 < NBUCK) ? bc[(i0 + 2) * NB + blk] : 0;
        int p3 = (i0 + 3 < NBUCK) ? bc[(i0 + 3) * NB + blk] : 0;
        int tsum = p0 + p1 + p2 + p3;
        int lane = t & 63, w = t >> 6;
        int incl = tsum;
#pragma unroll
        for (int off = 1; off < 64; off <<= 1) {
            int u = __shfl_up(incl, off);
            if (lane >= off) incl += u;
        }
        if (lane == 63) wsum[w] = incl;
        __syncthreads();
        int woff = 0;
        for (int k = 0; k < w; ++k) woff += wsum[k];
        int excl = woff + incl - tsum;
        if (i0 < NBUCK) { lbase[i0] = excl; lcur[i0] = excl; }
        if (i0 + 1 < NBUCK) { lbase[i0 + 1] = excl + p0; lcur[i0 + 1] = excl + p0; }
        if (i0 + 2 < NBUCK) { lbase[i0 + 2] = excl + p0 + p1; lcur[i0 + 2] = excl + p0 + p1; }
        if (i0 + 3 < NBUCK) { lbase[i0 + 3] = excl + p0 + p1 + p2; lcur[i0 + 3] = excl + p0 + p1 + p2; }
        if (t == 255) lbase[NBUCK] = excl + tsum;
    }
    __syncthreads();
    int lo = blk * CHUNK, hi = min(lo + CHUNK, TOT_E);
    int cnt = hi - lo;
    for (int i = lo + t; i < hi; i += 256) {
        int g, c; float v;
        if (i < N_EDGES) { g = item_rows[i]; c = item_cols[i]; v = item_vals[i]; }
        else { int j = i - N_EDGES; g = N_NODE + user_rows[j]; c = user_cols[j]; v = user_vals[j]; }
        int bk = g >> BSHIFT;
        int s = atomicAdd(&lcur[bk], 1);
        ebuf[s] = make_int2(((g & (BROWS - 1)) << 18) | c, __float_as_int(v));
        sbk[s] = (unsigned short)bk;
    }
    __syncthreads();
    for (int j = t; j < cnt; j += 256) {
        int k = sbk[j];
        staged[gb[k] + (j - lbase[k])] = ebuf[j];
    }
    for (int k = t; k < NBUCK; k += 256) {
        int c = lbase[k + 1] - lbase[k];
        int s = gb[k] + c, e = gb[k] + ((c + 7) & ~7);
        for (int q = s; q < e; ++q) staged[q] = make_int2(-1, 0);
    }
}

// phase 3: one WG per 512-row bucket; writes PACKED 4B edges into ecv.
__global__ void finalize_kernel(const int2* __restrict__ staged, const int* __restrict__ boffP,
                                const int* __restrict__ bbase,
                                int* __restrict__ row_ptr, unsigned* __restrict__ ecv) {
    __shared__ int hist[BROWS];
    __shared__ int start[BROWS + 1];
    __shared__ int2 ebuf[MAXH];
    __shared__ int wsum[4];
    int b = blockIdx.x, t = threadIdx.x;
    int base = boffP[b], end = boffP[b + 1];
    int ebase = bbase[b];
    hist[t * 2] = 0; hist[t * 2 + 1] = 0;
    __syncthreads();
    for (int k = base + t; k < end; k += 256) {
        int gx = staged[k].x;
        if (gx >= 0) atomicAdd(&hist[gx >> 18], 1);
    }
    __syncthreads();
    int i0 = t * 2;
    int c0 = hist[i0], c1 = hist[i0 + 1];
    int tsum = c0 + c1;
    int lane = t & 63, w = t >> 6;
    int incl = tsum;
#pragma unroll
    for (int off = 1; off < 64; off <<= 1) {
        int u = __shfl_up(incl, off);
        if (lane >= off) incl += u;
    }
    if (lane == 63) wsum[w] = incl;
    __syncthreads();
    int woff = 0;
    for (int k = 0; k < w; ++k) woff += wsum[k];
    int excl = woff + incl - tsum;
    start[i0] = excl; start[i0 + 1] = excl + c0;
    if (t == 255) start[BROWS] = excl + tsum;
    __syncthreads();
    int tot = start[BROWS];
#pragma unroll
    for (int q = 0; q < 2; ++q) {
        int r = i0 + q;
        int g = (b << BSHIFT) + r;
        if (g < NROWS_TOTAL) row_ptr[g] = ebase + start[r];
    }
    if (b == 0 && t == 0) row_ptr[NROWS_TOTAL] = TOT_E;
    if (tot <= MAXH) {
        hist[i0] = start[i0]; hist[i0 + 1] = start[i0 + 1];
        __syncthreads();
        for (int k = base + t; k < end; k += 256) {
            int2 p = staged[k];
            if (p.x < 0) continue;
            int l = atomicAdd(&hist[p.x >> 18], 1);
            ebuf[l] = make_int2(p.x & 0x3FFFF, p.y);
        }
        __syncthreads();
        for (int j = t; j < tot; j += 256) {
            int2 q = ebuf[j];
            ecv[ebase + j] = packcv(q.x, __int_as_float(q.y));
        }
    } else {
        hist[i0] = ebase + start[i0]; hist[i0 + 1] = ebase + start[i0 + 1];
        __syncthreads();
        for (int k = base + t; k < end; k += 256) {
            int2 p = staged[k];
            if (p.x < 0) continue;
            int pos = atomicAdd(&hist[p.x >> 18], 1);
            ecv[pos] = packcv(p.x & 0x3FFFF, __int_as_float(p.y));
        }
    }
}

// y = A x over ALL 2N rows (both channels). Gather offset selects channel half of x.
__global__ void spmm_y(const int* __restrict__ row_ptr, const unsigned* __restrict__ ecv,
                       const bfu* __restrict__ x,
                       bfu* __restrict__ y, float* __restrict__ rinv) {
    int t = threadIdx.x;
    int lane = t & 63;
    int sub = lane >> 4;
    int l16 = lane & 15;
    int i = blockIdx.x * 16 + (t >> 6) * 4 + sub;
    if (i >= NROWS_TOTAL) return;
    size_t off16 = (i >= N_NODE) ? (size_t)N_NODE * 16 : 0;
    int s = row_ptr[i], e = row_ptr[i + 1];
    const ushort4* x4 = (const ushort4*)x;
    float4 a = make_float4(0.f, 0.f, 0.f, 0.f);
    int gbase = sub * 16;
    for (int base = s; base < e; base += 16) {
        int idx = base + l16;
        unsigned pl = 0;
        if (idx < e) pl = ecv[idx];
        int cnt = min(16, e - base);
        int cnt4 = (cnt + 3) & ~3;
        for (int k = 0; k < cnt4; k += 4) {
#pragma unroll
            for (int u = 0; u < 4; ++u) {
                unsigned p = (unsigned)__shfl((int)pl, gbase + k + u);
                int c = p >> 14;
                float v = (float)(p & 16383u) * (1.0f / 16384.0f);
                ushort4 xv = x4[(size_t)c * 16 + off16 + l16];
                a.x += v * bf2f(xv.x); a.y += v * bf2f(xv.y);
                a.z += v * bf2f(xv.z); a.w += v * bf2f(xv.w);
            }
        }
    }
    size_t o4 = (size_t)i * 16 + l16;
    ushort4 bv;
    bv.x = f2bf(a.x); bv.y = f2bf(a.y); bv.z = f2bf(a.z); bv.w = f2bf(a.w);
    ((ushort4*)y)[o4] = bv;
    float sq = a.x * a.x + a.y * a.y + a.z * a.z + a.w * a.w;
#pragma unroll
    for (int off = 8; off; off >>= 1) sq += __shfl_xor(sq, off);
    if (l16 == 0) rinv[i] = 1.0f / fmaxf(sqrtf(sq), 1e-12f);
}

// Final: BOTH channels' layer-3 gathers + deferred sums + attention + mix in one pass.
// Row pair (i, N+i): e2 from first half, e3 from second half; no fp32 intermediate.
__global__ void spmm_fin(const int* __restrict__ row_ptr, const unsigned* __restrict__ ecv,
                         const bfu* __restrict__ y2 /* x for layer 3, 2N rows */,
                         const bfu* __restrict__ u0, const bfu* __restrict__ y1,
                         const float* __restrict__ rv1, const float* __restrict__ rv2,
                         float* __restrict__ mixed, const float* __restrict__ vvec,
                         float* __restrict__ score) {
    int t = threadIdx.x;
    int lane = t & 63;
    int sub = lane >> 4;
    int l16 = lane & 15;
    int i = blockIdx.x * 16 + (t >> 6) * 4 + sub;
    if (i >= N_NODE) return;
    const ushort4* x4 = (const ushort4*)y2;
    int gbase = sub * 16;
    // channel 2: item graph row i, gather from first half of y2
    float4 a2v = make_float4(0.f, 0.f, 0.f, 0.f);
    {
        int s = row_ptr[i], e = row_ptr[i + 1];
        for (int base = s; base < e; base += 16) {
            int idx = base + l16;
            unsigned pl = 0;
            if (idx < e) pl = ecv[idx];
            int cnt = min(16, e - base);
            int cnt4 = (cnt + 3) & ~3;
            for (int k = 0; k < cnt4; k += 4) {
#pragma unroll
                for (int u = 0; u < 4; ++u) {
                    unsigned p = (unsigned)__shfl((int)pl, gbase + k + u);
                    int c = p >> 14;
                    float v = (float)(p & 16383u) * (1.0f / 16384.0f);
                    ushort4 xv = x4[(size_t)c * 16 + l16];
                    a2v.x += v * bf2f(xv.x); a2v.y += v * bf2f(xv.y);
                    a2v.z += v * bf2f(xv.z); a2v.w += v * bf2f(xv.w);
                }
            }
        }
    }
    // channel 3: user graph row N+i, gather from second half of y2
    float4 a3v = make_float4(0.f, 0.f, 0.f, 0.f);
    {
        int s = row_ptr[N_NODE + i], e = row_ptr[N_NODE + i + 1];
        for (int base = s; base < e; base += 16) {
            int idx = base + l16;
            unsigned pl = 0;
            if (idx < e) pl = ecv[idx];
            int cnt = min(16, e - base);
            int cnt4 = (cnt + 3) & ~3;
            for (int k = 0; k < cnt4; k += 4) {
#pragma unroll
                for (int u = 0; u < 4; ++u) {
                    unsigned p = (unsigned)__shfl((int)pl, gbase + k + u);
                    int c = p >> 14;
                    float v = (float)(p & 16383u) * (1.0f / 16384.0f);
                    ushort4 xv = x4[(size_t)c * 16 + (size_t)N_NODE * 16 + l16];
                    a3v.x += v * bf2f(xv.x); a3v.y += v * bf2f(xv.y);
                    a3v.z += v * bf2f(xv.z); a3v.w += v * bf2f(xv.w);
                }
            }
        }
    }
    float sq2 = a2v.x * a2v.x + a2v.y * a2v.y + a2v.z * a2v.z + a2v.w * a2v.w;
    float sq3 = a3v.x * a3v.x + a3v.y * a3v.y + a3v.z * a3v.z + a3v.w * a3v.w;
#pragma unroll
    for (int off = 8; off; off >>= 1) {
        sq2 += __shfl_xor(sq2, off);
        sq3 += __shfl_xor(sq3, off);
    }
    float r3a = 1.0f / fmaxf(sqrtf(sq2), 1e-12f);
    float r3b = 1.0f / fmaxf(sqrtf(sq3), 1e-12f);
    size_t oA = (size_t)i * 16 + l16;
    size_t oB = (size_t)(N_NODE + i) * 16 + l16;
    float a1A = rv1[i], a2A = rv2[i];
    float a1B = rv1[N_NODE + i], a2B = rv2[N_NODE + i];
    ushort4 uA = ((const ushort4*)u0)[oA], uB = ((const ushort4*)u0)[oB];
    ushort4 y1A = ((const ushort4*)y1)[oA], y1B = ((const ushort4*)y1)[oB];
    ushort4 y2A = ((const ushort4*)y2)[oA], y2B = ((const ushort4*)y2)[oB];
    float4 e2, e3;
    e2.x = bf2f(uA.x) + a1A * bf2f(y1A.x) + a2A * bf2f(y2A.x) + r3a * a2v.x;
    e2.y = bf2f(uA.y) + a1A * bf2f(y1A.y) + a2A * bf2f(y2A.y) + r3a * a2v.y;
    e2.z = bf2f(uA.z) + a1A * bf2f(y1A.z) + a2A * bf2f(y2A.z) + r3a * a2v.z;
    e2.w = bf2f(uA.w) + a1A * bf2f(y1A.w) + a2A * bf2f(y2A.w) + r3a * a2v.w;
    e3.x = bf2f(uB.x) + a1B * bf2f(y1B.x) + a2B * bf2f(y2B.x) + r3b * a3v.x;
    e3.y = bf2f(uB.y) + a1B * bf2f(y1B.y) + a2B * bf2f(y2B.y) + r3b * a3v.y;
    e3.z = bf2f(uB.z) + a1B * bf2f(y1B.z) + a2B * bf2f(y2B.z) + r3b * a3v.z;
    e3.w = bf2f(uB.w) + a1B * bf2f(y1B.w) + a2B * bf2f(y2B.w) + r3b * a3v.w;
    float4 vv = ((const float4*)vvec)[l16];
    float w2 = e2.x * vv.x + e2.y * vv.y + e2.z * vv.z + e2.w * vv.w;
    float w3 = e3.x * vv.x + e3.y * vv.y + e3.z * vv.z + e3.w * vv.w;
#pragma unroll
    for (int off = 8; off; off >>= 1) {
        w2 += __shfl_xor(w2, off);
        w3 += __shfl_xor(w3, off);
    }
    float m = fmaxf(w2, w3);
    float x2 = __expf(w2 - m), x3 = __expf(w3 - m);
    float inv = 1.0f / (x2 + x3);
    float s2 = x2 * inv, s3 = x3 * inv;
    float4 o;
    o.x = s2 * e2.x + s3 * e3.x; o.y = s2 * e2.y + s3 * e3.y;
    o.z = s2 * e2.z + s3 * e3.z; o.w = s2 * e2.w + s3 * e3.w;
    ((float4*)mixed)[oA] = o;
    if (l16 == 0) { score[(size_t)i * 2] = s2; score[(size_t)i * 2 + 1] = s3; }
}

// v[k] = sum_j att_m[k][j] * att[j]
__global__ void vvec_kernel(const float* __restrict__ att_m, const float* __restrict__ att,
                            float* __restrict__ v) {
    int k = threadIdx.x;
    float s = 0.0f;
    for (int j = 0; j < 64; ++j) s += att_m[k * 64 + j] * att[j];
    v[k] = s;
}

extern "C" void kernel_launch(void* const* d_in, const int* in_sizes, int n_in,
                              void* d_out, int out_size, void* d_ws, size_t ws_size,
                              hipStream_t stream) {
    const float* user_emb = (const float*)d_in[0];
    const float* W0 = (const float*)d_in[1];
    const float* b0 = (const float*)d_in[2];
    const float* W1 = (const float*)d_in[3];
    const float* b1 = (const float*)d_in[4];
    const float* att = (const float*)d_in[5];
    const float* att_m = (const float*)d_in[6];
    const int* item_rows = (const int*)d_in[7];
    const int* item_cols = (const int*)d_in[8];
    const float* item_vals = (const float*)d_in[9];
    const int* user_rows = (const int*)d_in[10];
    const int* user_cols = (const int*)d_in[11];
    const float* user_vals = (const float*)d_in[12];

    float* out = (float*)d_out;
    float* mixed = out;
    float* score = out + (size_t)N_NODE * 64;

    char* w = (char*)d_ws;
    bfu* u0 = (bfu*)w;         w += (size_t)NROWS_TOTAL * 64 * 2;   // 51.2MB (both channels)
    bfu* y1 = (bfu*)w;         w += (size_t)NROWS_TOTAL * 64 * 2;
    bfu* y2 = (bfu*)w;         w += (size_t)NROWS_TOTAL * 64 * 2;
    float* rv1 = (float*)w;    w += (size_t)NROWS_TOTAL * 4;
    float* rv2 = (float*)w;    w += (size_t)NROWS_TOTAL * 4;
    int* row_ptr = (int*)w;    w += ((size_t)NROWS_TOTAL + 64) * 4;
    unsigned* ecv = (unsigned*)w; w += (size_t)TOT_E * 4;
    float* vvec = (float*)w;   w += 256;
    int* bc = (int*)w;         w += (size_t)SCAN_N * 4;
    int* soffP = (int*)w;      w += (size_t)SCAN_N * 4;
    int* bsumP = (int*)w;      w += (NBUCK + 8) * 4;
    int* btot = (int*)w;       w += (NBUCK + 8) * 4;
    int* boffP = (int*)w;      w += (NBUCK + 8) * 4;
    int* bbase = (int*)w;      w += (NBUCK + 8) * 4;
    // staged overlays u0..y2 (153.6MB >= padded worst case 76.9MB), dead during build
    int2* staged = (int2*)u0;

    const int NBALL = (NROWS_TOTAL + 15) / 16;   // 25000
    const int NB16 = (N_NODE + 15) / 16;         // 12500

    // counting-sort CSR build, padded line-exclusive staging, LDS-sorted burst writes
    binA_kernel<<<NB, 256, 0, stream>>>(item_rows, user_rows, bc);
    scan1_kernel<<<NBUCK, 256, 0, stream>>>(bc, bsumP, btot);
    scan2_kernel<<<1, 1024, 0, stream>>>(bsumP, btot, boffP, bbase);
    scan3_kernel<<<NBUCK, 256, 0, stream>>>(bc, boffP, soffP);
    binB_kernel<<<NB, 256, 0, stream>>>(item_rows, item_cols, item_vals,
                                        user_rows, user_cols, user_vals, bc, soffP, staged);
    finalize_kernel<<<NBUCK, 256, 0, stream>>>(staged, boffP, bbase, row_ptr, ecv);
    vvec_kernel<<<1, 64, 0, stream>>>(att_m, att, vvec);

    // both channels fused end-to-end over the unified 2N row space
    gate2_kernel<<<2 * GATE_B, 256, 0, stream>>>(user_emb, W0, b0, W1, b1, u0);
    spmm_y<<<NBALL, 256, 0, stream>>>(row_ptr, ecv, u0, y1, rv1);
    spmm_y<<<NBALL, 256, 0, stream>>>(row_ptr, ecv, y1, y2, rv2);
    spmm_fin<<<NB16, 256, 0, stream>>>(row_ptr, ecv, y2, u0, y1, rv1, rv2,
                                       mixed, vvec, score);
}

// Round 20
// 395.574 us; speedup vs baseline: 1.8154x; 1.0596x over previous
//
#include <hip/hip_runtime.h>

#define N_NODE 200000
#define EMB 64
#define N_EDGES 2000000
#define NROWS_TOTAL (2 * N_NODE)        // both graphs' rows concatenated
#define TOT_E (2 * N_EDGES)

// counting-sort geometry
#define BSHIFT 9
#define BROWS 512                                    // rows per bucket
#define NBUCK ((NROWS_TOTAL + BROWS - 1) / BROWS)    // 782
#define NB 1024                                      // binning blocks; == entries per bucket row
#define CHUNK ((TOT_E + NB - 1) / NB)                // 3907 edges per block
#define SCAN_N (NBUCK * NB)                          // 800768
#define MAXH 6144                                    // LDS edge buffer per bucket (mean ~5115)
#define GATE_B ((N_NODE / 16 + 15) / 16)             // 782 blocks per channel half

typedef unsigned short bfu;
typedef __attribute__((ext_vector_type(8))) short bf16x8;
typedef __attribute__((ext_vector_type(4))) float f32x4;

__device__ __forceinline__ float bf2f(bfu u) { return __uint_as_float(((unsigned)u) << 16); }
__device__ __forceinline__ bfu f2bf(float f) {
    unsigned b = __float_as_uint(f);
    return (bfu)((b + 0x7FFF + ((b >> 16) & 1)) >> 16);   // RTNE, finite inputs
}
// edge pack: col (18b) << 14 | val quantized to 14-bit fixed point in [0,1); err <= 3e-5
__device__ __forceinline__ unsigned packcv(int col, float v) {
    int q = (int)(v * 16384.0f + 0.5f);
    q = q < 0 ? 0 : (q > 16383 ? 16383 : q);
    return ((unsigned)col << 14) | (unsigned)q;
}

// Both channels' gating in one dispatch: half 0 -> W0/b0 -> u0[0..N), half 1 -> W1/b1 -> u0[N..2N)
__global__ void gate2_kernel(const float* __restrict__ emb,
                             const float* __restrict__ W0, const float* __restrict__ b0,
                             const float* __restrict__ W1, const float* __restrict__ b1,
                             bfu* __restrict__ out) {
    int blk = blockIdx.x;
    int half = (blk >= GATE_B) ? 1 : 0;
    const float* W = half ? W1 : W0;
    const float* b = half ? b1 : b0;
    bfu* o = out + (size_t)half * N_NODE * 64;
    int bblk = blk - half * GATE_B;
    int t = threadIdx.x;
    int w = t >> 6, lane = t & 63;
    int l16 = lane & 15, kg = lane >> 4;
    bf16x8 Bf[2][4];
#pragma unroll
    for (int kb = 0; kb < 2; ++kb)
#pragma unroll
        for (int nt = 0; nt < 4; ++nt) {
            bf16x8 f;
#pragma unroll
            for (int e = 0; e < 8; ++e)
                f[e] = (short)f2bf(W[(kb * 32 + kg * 8 + e) * 64 + nt * 16 + l16]);
            Bf[kb][nt] = f;
        }
    float bias[4];
#pragma unroll
    for (int nt = 0; nt < 4; ++nt) bias[nt] = b[nt * 16 + l16];
    const float4* e4 = (const float4*)emb;
#pragma unroll 1
    for (int it = 0; it < 4; ++it) {
        int tile = bblk * 16 + w * 4 + it;
        if (tile * 16 >= N_NODE) break;
        int arow = tile * 16 + l16;
        size_t ab = (size_t)arow * 16 + kg * 2;
        float4 a0 = e4[ab], a1 = e4[ab + 1];
        float4 a2 = e4[ab + 8], a3 = e4[ab + 9];
        bf16x8 A0, A1;
        A0[0] = (short)f2bf(a0.x); A0[1] = (short)f2bf(a0.y);
        A0[2] = (short)f2bf(a0.z); A0[3] = (short)f2bf(a0.w);
        A0[4] = (short)f2bf(a1.x); A0[5] = (short)f2bf(a1.y);
        A0[6] = (short)f2bf(a1.z); A0[7] = (short)f2bf(a1.w);
        A1[0] = (short)f2bf(a2.x); A1[1] = (short)f2bf(a2.y);
        A1[2] = (short)f2bf(a2.z); A1[3] = (short)f2bf(a2.w);
        A1[4] = (short)f2bf(a3.x); A1[5] = (short)f2bf(a3.y);
        A1[6] = (short)f2bf(a3.z); A1[7] = (short)f2bf(a3.w);
        f32x4 acc[4];
#pragma unroll
        for (int nt = 0; nt < 4; ++nt) {
            acc[nt] = (f32x4){0.f, 0.f, 0.f, 0.f};
            acc[nt] = __builtin_amdgcn_mfma_f32_16x16x32_bf16(A0, Bf[0][nt], acc[nt], 0, 0, 0);
            acc[nt] = __builtin_amdgcn_mfma_f32_16x16x32_bf16(A1, Bf[1][nt], acc[nt], 0, 0, 0);
        }
#pragma unroll
        for (int nt = 0; nt < 4; ++nt) {
#pragma unroll
            for (int r = 0; r < 4; ++r) {
                int orow = tile * 16 + kg * 4 + r;
                int col = nt * 16 + l16;
                float s = acc[nt][r] + bias[nt];
                float g = 1.0f / (1.0f + __expf(-s));
                float xv = emb[(size_t)orow * 64 + col];
                o[(size_t)orow * 64 + col] = f2bf(xv * g);
            }
        }
    }
}

// phase 1: per-block LDS bucket histogram -> bc[bucket*NB + blk]
__global__ void binA_kernel(const int* __restrict__ item_rows,
                            const int* __restrict__ user_rows,
                            int* __restrict__ bc) {
    __shared__ int h[NBUCK];
    int t = threadIdx.x, blk = blockIdx.x;
    for (int k = t; k < NBUCK; k += 256) h[k] = 0;
    __syncthreads();
    int lo = blk * CHUNK, hi = min(lo + CHUNK, TOT_E);
    for (int i = lo + t; i < hi; i += 256) {
        int g = (i < N_EDGES) ? item_rows[i] : (N_NODE + user_rows[i - N_EDGES]);
        atomicAdd(&h[g >> BSHIFT], 1);
    }
    __syncthreads();
    for (int k = t; k < NBUCK; k += 256) bc[k * NB + blk] = h[k];
}

// scan1: one block per bucket (NB==1024 entries). Outputs padded bucket total + real bucket total.
__global__ void scan1_kernel(const int* __restrict__ bc, int* __restrict__ bsumP,
                             int* __restrict__ btot) {
    int b = blockIdx.x, t = threadIdx.x;
    int base = b * NB + t * 4;
    int sR = 0, sP = 0;
#pragma unroll
    for (int k = 0; k < 4; ++k) {
        int c = bc[base + k];
        sR += c;
        sP += (c + 7) & ~7;
    }
#pragma unroll
    for (int off = 32; off; off >>= 1) {
        sR += __shfl_xor(sR, off);
        sP += __shfl_xor(sP, off);
    }
    __shared__ int wsR[4], wsP[4];
    int lane = t & 63, w = t >> 6;
    if (lane == 0) { wsR[w] = sR; wsP[w] = sP; }
    __syncthreads();
    if (t == 0) {
        btot[b] = wsR[0] + wsR[1] + wsR[2] + wsR[3];
        bsumP[b] = wsP[0] + wsP[1] + wsP[2] + wsP[3];
    }
}

// scan2: dual exclusive scan over NBUCK entries (1024 threads)
__global__ void scan2_kernel(const int* __restrict__ bsumP, const int* __restrict__ btot,
                             int* __restrict__ boffP, int* __restrict__ bbase) {
    __shared__ int sh[1024];
    int t = threadIdx.x;
    int vP = (t < NBUCK) ? bsumP[t] : 0;
    sh[t] = vP;
    __syncthreads();
    for (int off = 1; off < 1024; off <<= 1) {
        int u = (t >= off) ? sh[t - off] : 0;
        __syncthreads();
        sh[t] += u;
        __syncthreads();
    }
    if (t < NBUCK) boffP[t] = sh[t] - vP;
    if (t == 1023) boffP[NBUCK] = sh[1023];
    __syncthreads();
    int vR = (t < NBUCK) ? btot[t] : 0;
    sh[t] = vR;
    __syncthreads();
    for (int off = 1; off < 1024; off <<= 1) {
        int u = (t >= off) ? sh[t - off] : 0;
        __syncthreads();
        sh[t] += u;
        __syncthreads();
    }
    if (t < NBUCK) bbase[t] = sh[t] - vR;
}

// scan3: per-entry PADDED exclusive offsets within bucket, based at boffP[bucket]
__global__ void scan3_kernel(const int* __restrict__ bc, const int* __restrict__ boffP,
                             int* __restrict__ soffP) {
    int b = blockIdx.x, t = threadIdx.x;
    int lane = t & 63, w = t >> 6;
    int base = b * NB + t * 4;
    int p[4];
#pragma unroll
    for (int k = 0; k < 4; ++k) p[k] = (bc[base + k] + 7) & ~7;
    int e1 = p[0], e2 = p[0] + p[1], e3 = p[0] + p[1] + p[2];
    int tsum = e3 + p[3];
    int incl = tsum;
#pragma unroll
    for (int off = 1; off < 64; off <<= 1) {
        int u = __shfl_up(incl, off);
        if (lane >= off) incl += u;
    }
    int excl = incl - tsum;
    __shared__ int wsum[4];
    if (lane == 63) wsum[w] = incl;
    __syncthreads();
    int woff = 0;
    for (int k = 0; k < 4; ++k) if (k < w) woff += wsum[k];
    int g = boffP[b] + woff + excl;
    soffP[base + 0] = g;
    soffP[base + 1] = g + e1;
    soffP[base + 2] = g + e2;
    soffP[base + 3] = g + e3;
}

// phase 2: LDS counting sort + burst write, 512 threads (8 waves) for latency hiding.
__global__ void binB_kernel(const int* __restrict__ item_rows, const int* __restrict__ item_cols,
                            const float* __restrict__ item_vals,
                            const int* __restrict__ user_rows, const int* __restrict__ user_cols,
                            const float* __restrict__ user_vals,
                            const int* __restrict__ bc, const int* __restrict__ soffP,
                            int2* __restrict__ staged) {
    __shared__ int2 ebuf[CHUNK];
    __shared__ unsigned short sbk[CHUNK];
    __shared__ int lbase[NBUCK + 1];
    __shared__ int lcur[NBUCK];
    __shared__ int gb[NBUCK];
    __shared__ int wsum[8];
    int t = threadIdx.x, blk = blockIdx.x;
    for (int k = t; k < NBUCK; k += 512) gb[k] = soffP[k * NB + blk];
    {
        int i0 = t * 2;
        int p0 = (i0 < NBUCK) ? bc[i0 * NB + blk] : 0;
        int p1 = (i0 + 1 < NBUCK) ? bc[(i0 + 1) * NB + blk] : 0;
        int tsum = p0 + p1;
        int lane = t & 63, w = t >> 6;
        int incl = tsum;
#pragma unroll
        for (int off = 1; off < 64; off <<= 1) {
            int u = __shfl_up(incl, off);
            if (lane >= off) incl += u;
        }
        if (lane == 63) wsum[w] = incl;
        __syncthreads();
        int woff = 0;
        for (int k = 0; k < w; ++k) woff += wsum[k];
        int excl = woff + incl - tsum;
        if (i0 < NBUCK) { lbase[i0] = excl; lcur[i0] = excl; }
        if (i0 + 1 < NBUCK) { lbase[i0 + 1] = excl + p0; lcur[i0 + 1] = excl + p0; }
        if (t == 511) lbase[NBUCK] = excl + tsum;   // == edges in this chunk
    }
    __syncthreads();
    int lo = blk * CHUNK, hi = min(lo + CHUNK, TOT_E);
    int cnt = hi - lo;
    for (int i = lo + t; i < hi; i += 512) {
        int g, c; float v;
        if (i < N_EDGES) { g = item_rows[i]; c = item_cols[i]; v = item_vals[i]; }
        else { int j = i - N_EDGES; g = N_NODE + user_rows[j]; c = user_cols[j]; v = user_vals[j]; }
        int bk = g >> BSHIFT;
        int s = atomicAdd(&lcur[bk], 1);
        ebuf[s] = make_int2(((g & (BROWS - 1)) << 18) | c, __float_as_int(v));
        sbk[s] = (unsigned short)bk;
    }
    __syncthreads();
    for (int j = t; j < cnt; j += 512) {
        int k = sbk[j];
        staged[gb[k] + (j - lbase[k])] = ebuf[j];
    }
    for (int k = t; k < NBUCK; k += 512) {
        int c = lbase[k + 1] - lbase[k];
        int s = gb[k] + c, e = gb[k] + ((c + 7) & ~7);
        for (int q = s; q < e; ++q) staged[q] = make_int2(-1, 0);
    }
}

// phase 3: one WG (512 threads) per 512-row bucket; writes PACKED 4B edges into ecv.
__global__ void finalize_kernel(const int2* __restrict__ staged, const int* __restrict__ boffP,
                                const int* __restrict__ bbase,
                                int* __restrict__ row_ptr, unsigned* __restrict__ ecv) {
    __shared__ int hist[BROWS];
    __shared__ int start[BROWS + 1];
    __shared__ int2 ebuf[MAXH];
    __shared__ int wsum[8];
    int b = blockIdx.x, t = threadIdx.x;
    int base = boffP[b], end = boffP[b + 1];
    int ebase = bbase[b];
    hist[t] = 0;
    __syncthreads();
    for (int k = base + t; k < end; k += 512) {
        int gx = staged[k].x;
        if (gx >= 0) atomicAdd(&hist[gx >> 18], 1);
    }
    __syncthreads();
    int c = hist[t];
    int lane = t & 63, w = t >> 6;
    int incl = c;
#pragma unroll
    for (int off = 1; off < 64; off <<= 1) {
        int u = __shfl_up(incl, off);
        if (lane >= off) incl += u;
    }
    if (lane == 63) wsum[w] = incl;
    __syncthreads();
    int woff = 0;
    for (int k = 0; k < w; ++k) woff += wsum[k];
    int excl = woff + incl - c;
    start[t] = excl;
    if (t == 511) start[BROWS] = excl + c;
    __syncthreads();
    int tot = start[BROWS];
    {
        int g = (b << BSHIFT) + t;
        if (g < NROWS_TOTAL) row_ptr[g] = ebase + start[t];
    }
    if (b == 0 && t == 0) row_ptr[NROWS_TOTAL] = TOT_E;
    if (tot <= MAXH) {
        hist[t] = start[t];
        __syncthreads();
        for (int k = base + t; k < end; k += 512) {
            int2 p = staged[k];
            if (p.x < 0) continue;
            int l = atomicAdd(&hist[p.x >> 18], 1);
            ebuf[l] = make_int2(p.x & 0x3FFFF, p.y);
        }
        __syncthreads();
        for (int j = t; j < tot; j += 512) {
            int2 q = ebuf[j];
            ecv[ebase + j] = packcv(q.x, __int_as_float(q.y));
        }
    } else {
        hist[t] = ebase + start[t];
        __syncthreads();
        for (int k = base + t; k < end; k += 512) {
            int2 p = staged[k];
            if (p.x < 0) continue;
            int pos = atomicAdd(&hist[p.x >> 18], 1);
            ecv[pos] = packcv(p.x & 0x3FFFF, __int_as_float(p.y));
        }
    }
}

// y = A x over ALL 2N rows (both channels). Gather offset selects channel half of x.
__global__ void spmm_y(const int* __restrict__ row_ptr, const unsigned* __restrict__ ecv,
                       const bfu* __restrict__ x,
                       bfu* __restrict__ y, float* __restrict__ rinv) {
    int t = threadIdx.x;
    int lane = t & 63;
    int sub = lane >> 4;
    int l16 = lane & 15;
    int i = blockIdx.x * 16 + (t >> 6) * 4 + sub;
    if (i >= NROWS_TOTAL) return;
    size_t off16 = (i >= N_NODE) ? (size_t)N_NODE * 16 : 0;
    int s = row_ptr[i], e = row_ptr[i + 1];
    const ushort4* x4 = (const ushort4*)x;
    float4 a = make_float4(0.f, 0.f, 0.f, 0.f);
    int gbase = sub * 16;
    for (int base = s; base < e; base += 16) {
        int idx = base + l16;
        unsigned pl = 0;
        if (idx < e) pl = ecv[idx];
        int cnt = min(16, e - base);
        int cnt4 = (cnt + 3) & ~3;
        for (int k = 0; k < cnt4; k += 4) {
#pragma unroll
            for (int u = 0; u < 4; ++u) {
                unsigned p = (unsigned)__shfl((int)pl, gbase + k + u);
                int c = p >> 14;
                float v = (float)(p & 16383u) * (1.0f / 16384.0f);
                ushort4 xv = x4[(size_t)c * 16 + off16 + l16];
                a.x += v * bf2f(xv.x); a.y += v * bf2f(xv.y);
                a.z += v * bf2f(xv.z); a.w += v * bf2f(xv.w);
            }
        }
    }
    size_t o4 = (size_t)i * 16 + l16;
    ushort4 bv;
    bv.x = f2bf(a.x); bv.y = f2bf(a.y); bv.z = f2bf(a.z); bv.w = f2bf(a.w);
    ((ushort4*)y)[o4] = bv;
    float sq = a.x * a.x + a.y * a.y + a.z * a.z + a.w * a.w;
#pragma unroll
    for (int off = 8; off; off >>= 1) sq += __shfl_xor(sq, off);
    if (l16 == 0) rinv[i] = 1.0f / fmaxf(sqrtf(sq), 1e-12f);
}

// Final: BOTH channels' layer-3 gathers + deferred sums + attention + mix in one pass.
__global__ void spmm_fin(const int* __restrict__ row_ptr, const unsigned* __restrict__ ecv,
                         const bfu* __restrict__ y2 /* x for layer 3, 2N rows */,
                         const bfu* __restrict__ u0, const bfu* __restrict__ y1,
                         const float* __restrict__ rv1, const float* __restrict__ rv2,
                         float* __restrict__ mixed, const float* __restrict__ vvec,
                         float* __restrict__ score) {
    int t = threadIdx.x;
    int lane = t & 63;
    int sub = lane >> 4;
    int l16 = lane & 15;
    int i = blockIdx.x * 16 + (t >> 6) * 4 + sub;
    if (i >= N_NODE) return;
    const ushort4* x4 = (const ushort4*)y2;
    int gbase = sub * 16;
    float4 a2v = make_float4(0.f, 0.f, 0.f, 0.f);
    {
        int s = row_ptr[i], e = row_ptr[i + 1];
        for (int base = s; base < e; base += 16) {
            int idx = base + l16;
            unsigned pl = 0;
            if (idx < e) pl = ecv[idx];
            int cnt = min(16, e - base);
            int cnt4 = (cnt + 3) & ~3;
            for (int k = 0; k < cnt4; k += 4) {
#pragma unroll
                for (int u = 0; u < 4; ++u) {
                    unsigned p = (unsigned)__shfl((int)pl, gbase + k + u);
                    int c = p >> 14;
                    float v = (float)(p & 16383u) * (1.0f / 16384.0f);
                    ushort4 xv = x4[(size_t)c * 16 + l16];
                    a2v.x += v * bf2f(xv.x); a2v.y += v * bf2f(xv.y);
                    a2v.z += v * bf2f(xv.z); a2v.w += v * bf2f(xv.w);
                }
            }
        }
    }
    float4 a3v = make_float4(0.f, 0.f, 0.f, 0.f);
    {
        int s = row_ptr[N_NODE + i], e = row_ptr[N_NODE + i + 1];
        for (int base = s; base < e; base += 16) {
            int idx = base + l16;
            unsigned pl = 0;
            if (idx < e) pl = ecv[idx];
            int cnt = min(16, e - base);
            int cnt4 = (cnt + 3) & ~3;
            for (int k = 0; k < cnt4; k += 4) {
#pragma unroll
                for (int u = 0; u < 4; ++u) {
                    unsigned p = (unsigned)__shfl((int)pl, gbase + k + u);
                    int c = p >> 14;
                    float v = (float)(p & 16383u) * (1.0f / 16384.0f);
                    ushort4 xv = x4[(size_t)c * 16 + (size_t)N_NODE * 16 + l16];
                    a3v.x += v * bf2f(xv.x); a3v.y += v * bf2f(xv.y);
                    a3v.z += v * bf2f(xv.z); a3v.w += v * bf2f(xv.w);
                }
            }
        }
    }
    float sq2 = a2v.x * a2v.x + a2v.y * a2v.y + a2v.z * a2v.z + a2v.w * a2v.w;
    float sq3 = a3v.x * a3v.x + a3v.y * a3v.y + a3v.z * a3v.z + a3v.w * a3v.w;
#pragma unroll
    for (int off = 8; off; off >>= 1) {
        sq2 += __shfl_xor(sq2, off);
        sq3 += __shfl_xor(sq3, off);
    }
    float r3a = 1.0f / fmaxf(sqrtf(sq2), 1e-12f);
    float r3b = 1.0f / fmaxf(sqrtf(sq3), 1e-12f);
    size_t oA = (size_t)i * 16 + l16;
    size_t oB = (size_t)(N_NODE + i) * 16 + l16;
    float a1A = rv1[i], a2A = rv2[i];
    float a1B = rv1[N_NODE + i], a2B = rv2[N_NODE + i];
    ushort4 uA = ((const ushort4*)u0)[oA], uB = ((const ushort4*)u0)[oB];
    ushort4 y1A = ((const ushort4*)y1)[oA], y1B = ((const ushort4*)y1)[oB];
    ushort4 y2A = ((const ushort4*)y2)[oA], y2B = ((const ushort4*)y2)[oB];
    float4 e2, e3;
    e2.x = bf2f(uA.x) + a1A * bf2f(y1A.x) + a2A * bf2f(y2A.x) + r3a * a2v.x;
    e2.y = bf2f(uA.y) + a1A * bf2f(y1A.y) + a2A * bf2f(y2A.y) + r3a * a2v.y;
    e2.z = bf2f(uA.z) + a1A * bf2f(y1A.z) + a2A * bf2f(y2A.z) + r3a * a2v.z;
    e2.w = bf2f(uA.w) + a1A * bf2f(y1A.w) + a2A * bf2f(y2A.w) + r3a * a2v.w;
    e3.x = bf2f(uB.x) + a1B * bf2f(y1B.x) + a2B * bf2f(y2B.x) + r3b * a3v.x;
    e3.y = bf2f(uB.y) + a1B * bf2f(y1B.y) + a2B * bf2f(y2B.y) + r3b * a3v.y;
    e3.z = bf2f(uB.z) + a1B * bf2f(y1B.z) + a2B * bf2f(y2B.z) + r3b * a3v.z;
    e3.w = bf2f(uB.w) + a1B * bf2f(y1B.w) + a2B * bf2f(y2B.w) + r3b * a3v.w;
    float4 vv = ((const float4*)vvec)[l16];
    float w2 = e2.x * vv.x + e2.y * vv.y + e2.z * vv.z + e2.w * vv.w;
    float w3 = e3.x * vv.x + e3.y * vv.y + e3.z * vv.z + e3.w * vv.w;
#pragma unroll
    for (int off = 8; off; off >>= 1) {
        w2 += __shfl_xor(w2, off);
        w3 += __shfl_xor(w3, off);
    }
    float m = fmaxf(w2, w3);
    float x2 = __expf(w2 - m), x3 = __expf(w3 - m);
    float inv = 1.0f / (x2 + x3);
    float s2 = x2 * inv, s3 = x3 * inv;
    float4 o;
    o.x = s2 * e2.x + s3 * e3.x; o.y = s2 * e2.y + s3 * e3.y;
    o.z = s2 * e2.z + s3 * e3.z; o.w = s2 * e2.w + s3 * e3.w;
    ((float4*)mixed)[oA] = o;
    if (l16 == 0) { score[(size_t)i * 2] = s2; score[(size_t)i * 2 + 1] = s3; }
}

// v[k] = sum_j att_m[k][j] * att[j]
__global__ void vvec_kernel(const float* __restrict__ att_m, const float* __restrict__ att,
                            float* __restrict__ v) {
    int k = threadIdx.x;
    float s = 0.0f;
    for (int j = 0; j < 64; ++j) s += att_m[k * 64 + j] * att[j];
    v[k] = s;
}

extern "C" void kernel_launch(void* const* d_in, const int* in_sizes, int n_in,
                              void* d_out, int out_size, void* d_ws, size_t ws_size,
                              hipStream_t stream) {
    const float* user_emb = (const float*)d_in[0];
    const float* W0 = (const float*)d_in[1];
    const float* b0 = (const float*)d_in[2];
    const float* W1 = (const float*)d_in[3];
    const float* b1 = (const float*)d_in[4];
    const float* att = (const float*)d_in[5];
    const float* att_m = (const float*)d_in[6];
    const int* item_rows = (const int*)d_in[7];
    const int* item_cols = (const int*)d_in[8];
    const float* item_vals = (const float*)d_in[9];
    const int* user_rows = (const int*)d_in[10];
    const int* user_cols = (const int*)d_in[11];
    const float* user_vals = (const float*)d_in[12];

    float* out = (float*)d_out;
    float* mixed = out;
    float* score = out + (size_t)N_NODE * 64;

    char* w = (char*)d_ws;
    bfu* u0 = (bfu*)w;         w += (size_t)NROWS_TOTAL * 64 * 2;
    bfu* y1 = (bfu*)w;         w += (size_t)NROWS_TOTAL * 64 * 2;
    bfu* y2 = (bfu*)w;         w += (size_t)NROWS_TOTAL * 64 * 2;
    float* rv1 = (float*)w;    w += (size_t)NROWS_TOTAL * 4;
    float* rv2 = (float*)w;    w += (size_t)NROWS_TOTAL * 4;
    int* row_ptr = (int*)w;    w += ((size_t)NROWS_TOTAL + 64) * 4;
    unsigned* ecv = (unsigned*)w; w += (size_t)TOT_E * 4;
    float* vvec = (float*)w;   w += 256;
    int* bc = (int*)w;         w += (size_t)SCAN_N * 4;
    int* soffP = (int*)w;      w += (size_t)SCAN_N * 4;
    int* bsumP = (int*)w;      w += (NBUCK + 8) * 4;
    int* btot = (int*)w;       w += (NBUCK + 8) * 4;
    int* boffP = (int*)w;      w += (NBUCK + 8) * 4;
    int* bbase = (int*)w;      w += (NBUCK + 8) * 4;
    int2* staged = (int2*)u0;  // overlays u0..y2 (153.6MB), dead during build

    const int NBALL = (NROWS_TOTAL + 15) / 16;   // 25000
    const int NB16 = (N_NODE + 15) / 16;         // 12500

    binA_kernel<<<NB, 256, 0, stream>>>(item_rows, user_rows, bc);
    scan1_kernel<<<NBUCK, 256, 0, stream>>>(bc, bsumP, btot);
    scan2_kernel<<<1, 1024, 0, stream>>>(bsumP, btot, boffP, bbase);
    scan3_kernel<<<NBUCK, 256, 0, stream>>>(bc, boffP, soffP);
    binB_kernel<<<NB, 512, 0, stream>>>(item_rows, item_cols, item_vals,
                                        user_rows, user_cols, user_vals, bc, soffP, staged);
    finalize_kernel<<<NBUCK, 512, 0, stream>>>(staged, boffP, bbase, row_ptr, ecv);
    vvec_kernel<<<1, 64, 0, stream>>>(att_m, att, vvec);

    gate2_kernel<<<2 * GATE_B, 256, 0, stream>>>(user_emb, W0, b0, W1, b1, u0);
    spmm_y<<<NBALL, 256, 0, stream>>>(row_ptr, ecv, u0, y1, rv1);
    spmm_y<<<NBALL, 256, 0, stream>>>(row_ptr, ecv, y1, y2, rv2);
    spmm_fin<<<NB16, 256, 0, stream>>>(row_ptr, ecv, y2, u0, y1, rv1, rv2,
                                       mixed, vvec, score);
}